// Round 3
// baseline (3800.207 us; speedup 1.0000x reference)
//
#include <hip/hip_runtime.h>

typedef unsigned short u16;
typedef __bf16 bf16x8 __attribute__((ext_vector_type(8)));
typedef float f32x4 __attribute__((ext_vector_type(4)));

#define BATCH 32768L

__device__ __forceinline__ u16 f2b(float f) {
  union { float f; unsigned int u; } v; v.f = f;
  unsigned int r = v.u + 0x7fffu + ((v.u >> 16) & 1u);
  return (u16)(r >> 16);
}
__device__ __forceinline__ float b2f(u16 h) {
  union { unsigned int u; float f; } v; v.u = ((unsigned int)h) << 16;
  return v.f;
}
__device__ __forceinline__ float sigf(float x) { return 1.f / (1.f + __expf(-x)); }
__device__ __forceinline__ float tanh_f(float x) { return 2.f / (1.f + __expf(-2.f * x)) - 1.f; }

// ---------------- strided f32 -> bf16 convert ----------------
__global__ void cvt_kernel(const float* __restrict__ src, u16* __restrict__ dst,
                           long rows, int scols, int dstride) {
  long n = rows * (long)scols;
  for (long i = (long)blockIdx.x * blockDim.x + threadIdx.x; i < n;
       i += (long)gridDim.x * blockDim.x) {
    long r = i / scols; int c = (int)(i - r * scols);
    dst[r * (long)dstride + c] = f2b(src[i]);
  }
}

__global__ void bias_sum_kernel(const float* __restrict__ a, const float* __restrict__ b,
                                float* __restrict__ o, int n) {
  int i = blockIdx.x * 256 + threadIdx.x;
  if (i < n) o[i] = a[i] + b[i];
}

// writes last_cbc (cols 0..5) of dec_in for a chunk; cbc already offset to chunk
__global__ void init_last_kernel(const float* __restrict__ cbc, u16* __restrict__ dec_in, long n) {
  long i = (long)blockIdx.x * 256 + threadIdx.x;
  if (i < n) {
    long r = i / 6; int j = (int)(i - r * 6);
    dec_in[r * 392 + j] = f2b(cbc[r * 18 + 12 + j]);
  }
}

// ---------------- generic MFMA GEMM: C = act(A1@W1^T + A2@W2^T + bias) ----------------
// Block: 64 rows x (ngroups x 64) cols, 4 waves (wave w owns rows [w*16, w*16+16)).
// W row index for (group g, in-group col c) = g*gs + blockIdx.y*ys + c.
// EPI=0: store bf16 (+bias, optional relu), out col = W row index.
// EPI=1: LSTM gating (gs=256, ys=64): acc[g] = gate g; writes h (bf16) and c (f32).
template <int EPI>
__global__ __launch_bounds__(256)
void mfma_gemm(const u16* __restrict__ A1, int lda1, int K1, const u16* __restrict__ W1, int wld1,
               const u16* __restrict__ A2, int lda2, int K2, const u16* __restrict__ W2, int wld2,
               int gs, int ys, int ngroups, const float* __restrict__ bias,
               u16* __restrict__ out0, int ldo, int relu,
               const float* __restrict__ cprev, float* __restrict__ cout,
               u16* __restrict__ hout, int ldh)
{
  __shared__ u16 As[64 * 40];       // 64 x 32, padded to 40
  __shared__ u16 Bs[4 * 64 * 40];   // 4 groups x 64 x 32, padded
  const int tid = threadIdx.x;
  const int l = tid & 63, w = tid >> 6;
  const long bm = (long)blockIdx.x * 64;
  const int yb = blockIdx.y;

  f32x4 acc[4][4];
#pragma unroll
  for (int g = 0; g < 4; ++g)
#pragma unroll
    for (int n = 0; n < 4; ++n) acc[g][n] = (f32x4){0.f, 0.f, 0.f, 0.f};

  const int ar = tid >> 2, akc = (tid & 3) * 8;   // A staging: row, k-offset
  const int bg = tid >> 6, br = tid & 63;         // B staging: group, in-group row
  const int arow = w * 16 + (l & 15);
  const int koff = (l >> 4) * 8;

  for (int src = 0; src < 2; ++src) {
    const u16* A = src ? A2 : A1;
    const u16* W = src ? W2 : W1;
    const int K = src ? K2 : K1;
    const int lda = src ? lda2 : lda1;
    const int wld = src ? wld2 : wld1;
    if (A == nullptr) continue;
    const int nch = (K + 31) >> 5;
    for (int ch = 0; ch < nch; ++ch) {
      const int kb = ch << 5;
      { // stage A tile
        const u16* ap = A + (bm + ar) * (long)lda + (kb + akc);
        int4 tmp;
        u16* v = (u16*)&tmp;
        if (kb + akc + 8 <= K && ((((size_t)ap) & 15) == 0)) {
          tmp = *(const int4*)ap;
        } else {
#pragma unroll
          for (int j = 0; j < 8; ++j) v[j] = (kb + akc + j < K) ? ap[j] : (u16)0;
        }
        *(int4*)&As[ar * 40 + akc] = tmp;
      }
      if (bg < ngroups) { // stage B (weights) tile
        const long wrow = (long)bg * gs + (long)yb * ys + br;
        const u16* wp = W + wrow * (long)wld + kb;
#pragma unroll
        for (int q8 = 0; q8 < 4; ++q8) {
          int4 tmp;
          u16* v = (u16*)&tmp;
          const u16* wq = wp + q8 * 8;
          if (kb + q8 * 8 + 8 <= K && ((((size_t)wq) & 15) == 0)) {
            tmp = *(const int4*)wq;
          } else {
#pragma unroll
            for (int j = 0; j < 8; ++j) v[j] = (kb + q8 * 8 + j < K) ? wq[j] : (u16)0;
          }
          *(int4*)&Bs[(bg * 64 + br) * 40 + q8 * 8] = tmp;
        }
      }
      __syncthreads();
      bf16x8 af = *(const bf16x8*)&As[arow * 40 + koff];
#pragma unroll
      for (int g = 0; g < 4; ++g) {
        if (g < ngroups) {
#pragma unroll
          for (int n = 0; n < 4; ++n) {
            bf16x8 bfr = *(const bf16x8*)&Bs[(g * 64 + n * 16 + (l & 15)) * 40 + koff];
            acc[g][n] = __builtin_amdgcn_mfma_f32_16x16x32_bf16(af, bfr, acc[g][n], 0, 0, 0);
          }
        }
      }
      __syncthreads();
    }
  }

  const int colb = l & 15;
  const int rq = l >> 4;
  if (EPI == 0) {
    for (int g = 0; g < ngroups; ++g) {
#pragma unroll
      for (int n = 0; n < 4; ++n) {
        const int wrow = g * gs + yb * ys + n * 16 + colb;
        const float bi = bias ? bias[wrow] : 0.f;
#pragma unroll
        for (int r = 0; r < 4; ++r) {
          const long row = bm + w * 16 + rq * 4 + r;
          float vv = acc[g][n][r] + bi;
          if (relu) vv = fmaxf(vv, 0.f);
          out0[row * (long)ldo + wrow] = f2b(vv);
        }
      }
    }
  } else {
#pragma unroll
    for (int n = 0; n < 4; ++n) {
      const int cb = yb * 64 + n * 16 + colb;
      const float b_i = bias[cb];
      const float b_f = bias[256 + cb];
      const float b_g = bias[512 + cb];
      const float b_o = bias[768 + cb];
#pragma unroll
      for (int r = 0; r < 4; ++r) {
        const long row = bm + w * 16 + rq * 4 + r;
        const float zi = acc[0][n][r] + b_i;
        const float zf = acc[1][n][r] + b_f;
        const float zg = acc[2][n][r] + b_g;
        const float zo = acc[3][n][r] + b_o;
        const float cp = cprev ? cprev[row * 256 + cb] : 0.f;
        const float cn = sigf(zf) * cp + sigf(zi) * tanh_f(zg);
        const float hn = sigf(zo) * tanh_f(cn);
        cout[row * 256 + cb] = cn;
        hout[row * (long)ldh + cb] = f2b(hn);
      }
    }
  }
}

// ---------------- baseline MLP + LayerNorm -> dec_in[:, 262:390] ----------------
__global__ __launch_bounds__(256)
void baseline_kernel(const float* __restrict__ baseline, const float* __restrict__ Wb,
                     const float* __restrict__ bb, const float* __restrict__ ln_g,
                     const float* __restrict__ ln_b, u16* __restrict__ dec_in)
{
  __shared__ float wbs[1280];
  __shared__ float bbs[128], lgs[128], lbs[128];
  const int tid = threadIdx.x;
  for (int i = tid; i < 1280; i += 256) wbs[i] = Wb[i];
  if (tid < 128) { bbs[tid] = bb[tid]; lgs[tid] = ln_g[tid]; lbs[tid] = ln_b[tid]; }
  __syncthreads();
  const int l = tid & 63, w = tid >> 6;
  const long row = (long)blockIdx.x * 4 + w;
  float bl[10];
#pragma unroll
  for (int k = 0; k < 10; ++k) bl[k] = baseline[row * 10 + k];
  const int c0 = l, c1 = l + 64;
  float z0 = bbs[c0], z1 = bbs[c1];
#pragma unroll
  for (int k = 0; k < 10; ++k) { z0 += bl[k] * wbs[c0 * 10 + k]; z1 += bl[k] * wbs[c1 * 10 + k]; }
  z0 = fmaxf(z0, 0.f); z1 = fmaxf(z1, 0.f);
  float s = z0 + z1, sq = z0 * z0 + z1 * z1;
#pragma unroll
  for (int m = 32; m; m >>= 1) { s += __shfl_xor(s, m); sq += __shfl_xor(sq, m); }
  const float mu = s * (1.f / 128.f);
  const float var = sq * (1.f / 128.f) - mu * mu;
  const float rs = rsqrtf(var + 1e-5f);
  dec_in[row * 392 + 262 + c0] = f2b((z0 - mu) * rs * lgs[c0] + lbs[c0]);
  dec_in[row * 392 + 262 + c1] = f2b((z1 - mu) * rs * lgs[c1] + lbs[c1]);
}

// ---------------- attention: scores -> softmax(3) -> context -> dec_in[:, 6:262] ----------------
__global__ __launch_bounds__(256)
void attn_kernel(const u16* __restrict__ q, const u16* __restrict__ ep,
                 const u16* __restrict__ eo, const float* __restrict__ va,
                 const float* __restrict__ ba, u16* __restrict__ dec_in)
{
  const int tid = threadIdx.x;
  const int l = tid & 63, w = tid >> 6;
  const long row = (long)blockIdx.x * 4 + w;
  const int c = l * 4;
  float qv[4], vav[4];
  {
    ushort4 qu = *(const ushort4*)&q[row * 256 + c];
    qv[0] = b2f(qu.x); qv[1] = b2f(qu.y); qv[2] = b2f(qu.z); qv[3] = b2f(qu.w);
    float4 vv = *(const float4*)&va[c];
    vav[0] = vv.x; vav[1] = vv.y; vav[2] = vv.z; vav[3] = vv.w;
  }
  float s[3];
#pragma unroll
  for (int t = 0; t < 3; ++t) {
    ushort4 eu = *(const ushort4*)&ep[row * 768 + t * 256 + c];
    float p = tanh_f(qv[0] + b2f(eu.x)) * vav[0]
            + tanh_f(qv[1] + b2f(eu.y)) * vav[1]
            + tanh_f(qv[2] + b2f(eu.z)) * vav[2]
            + tanh_f(qv[3] + b2f(eu.w)) * vav[3];
#pragma unroll
    for (int m = 32; m; m >>= 1) p += __shfl_xor(p, m);
    s[t] = p + ba[0];
  }
  const float mx = fmaxf(s[0], fmaxf(s[1], s[2]));
  const float e0 = __expf(s[0] - mx), e1 = __expf(s[1] - mx), e2 = __expf(s[2] - mx);
  const float inv = 1.f / (e0 + e1 + e2);
  const float w0 = e0 * inv, w1 = e1 * inv, w2 = e2 * inv;
  const ushort4 a0 = *(const ushort4*)&eo[row * 768 + 0 * 256 + c];
  const ushort4 a1 = *(const ushort4*)&eo[row * 768 + 1 * 256 + c];
  const ushort4 a2 = *(const ushort4*)&eo[row * 768 + 2 * 256 + c];
  u16* dp = &dec_in[row * 392 + 6 + c];
  dp[0] = f2b(w0 * b2f(a0.x) + w1 * b2f(a1.x) + w2 * b2f(a2.x));
  dp[1] = f2b(w0 * b2f(a0.y) + w1 * b2f(a1.y) + w2 * b2f(a2.y));
  dp[2] = f2b(w0 * b2f(a0.z) + w1 * b2f(a1.z) + w2 * b2f(a2.z));
  dp[3] = f2b(w0 * b2f(a0.w) + w1 * b2f(a1.w) + w2 * b2f(a2.w));
}

// ---------------- output head tail: delta = t1 @ Wo2^T + bo2; pred = last + delta ----------------
__global__ __launch_bounds__(256)
void delta_kernel(const u16* __restrict__ t1, const float* __restrict__ Wo2,
                  const float* __restrict__ bo2, const float* __restrict__ lastp, int lstride,
                  float* __restrict__ outp, int ostride, u16* __restrict__ dec_in)
{
  __shared__ float w2s[768];
  __shared__ float part[64][4][6];
  const int tid = threadIdx.x;
  for (int i = tid; i < 768; i += 256) w2s[i] = Wo2[i];
  __syncthreads();
  const int rw = tid >> 2, q = tid & 3;
  const long row = (long)blockIdx.x * 64 + rw;
  float p[6] = {0.f, 0.f, 0.f, 0.f, 0.f, 0.f};
  const u16* tp = &t1[row * 128 + q * 32];
#pragma unroll
  for (int it = 0; it < 4; ++it) {
    int4 chunk = *(const int4*)&tp[it * 8];
    const u16* cu = (const u16*)&chunk;
#pragma unroll
    for (int e = 0; e < 8; ++e) {
      const float tv = b2f(cu[e]);
      const int k = q * 32 + it * 8 + e;
#pragma unroll
      for (int j = 0; j < 6; ++j) p[j] += tv * w2s[j * 128 + k];
    }
  }
#pragma unroll
  for (int j = 0; j < 6; ++j) part[rw][q][j] = p[j];
  __syncthreads();
  if (tid < 64) {
    const long r2 = (long)blockIdx.x * 64 + tid;
#pragma unroll
    for (int j = 0; j < 6; ++j) {
      const float d = bo2[j] + part[tid][0][j] + part[tid][1][j] + part[tid][2][j] + part[tid][3][j];
      const float pr = lastp[r2 * lstride + j] + d;
      outp[r2 * ostride + j] = pr;
      dec_in[r2 * 392 + j] = f2b(pr);
    }
  }
}

extern "C" void kernel_launch(void* const* d_in, const int* in_sizes, int n_in,
                              void* d_out, int out_size, void* d_ws, size_t ws_size,
                              hipStream_t stream) {
  const float* cbc   = (const float*)d_in[0];
  const float* base  = (const float*)d_in[1];
  const float* W_ih0 = (const float*)d_in[2];
  const float* W_hh0 = (const float*)d_in[3];
  const float* b_ih0 = (const float*)d_in[4];
  const float* b_hh0 = (const float*)d_in[5];
  const float* W_ih1 = (const float*)d_in[6];
  const float* W_hh1 = (const float*)d_in[7];
  const float* b_ih1 = (const float*)d_in[8];
  const float* b_hh1 = (const float*)d_in[9];
  const float* Wb    = (const float*)d_in[10];
  const float* bb    = (const float*)d_in[11];
  const float* ln_g  = (const float*)d_in[12];
  const float* ln_b  = (const float*)d_in[13];
  const float* W1a   = (const float*)d_in[14];
  const float* b1a   = (const float*)d_in[15];
  const float* W2a   = (const float*)d_in[16];
  const float* b2a   = (const float*)d_in[17];
  const float* va    = (const float*)d_in[18];
  const float* ba    = (const float*)d_in[19];
  const float* Wd_ih = (const float*)d_in[20];
  const float* Wd_hh = (const float*)d_in[21];
  const float* bd_ih = (const float*)d_in[22];
  const float* bd_hh = (const float*)d_in[23];
  const float* Wo1   = (const float*)d_in[24];
  const float* bo1   = (const float*)d_in[25];
  const float* Wo2   = (const float*)d_in[26];
  const float* bo2   = (const float*)d_in[27];
  float* out = (float*)d_out;
  (void)in_sizes; (void)n_in; (void)out_size;

  unsigned char* wsb = (unsigned char*)d_ws;
  size_t off = 0;
  auto alloc = [&](size_t bytes) -> void* {
    void* p = wsb + off;
    off += (bytes + 255) & ~(size_t)255;
    return p;
  };
  // ---- persistent (weights, biases): ~3.3 MB ----
  u16* wih0b = (u16*)alloc(1024 * 6 * 2);
  u16* whh0b = (u16*)alloc(1024 * 256 * 2);
  u16* wih1b = (u16*)alloc(1024 * 256 * 2);
  u16* whh1b = (u16*)alloc(1024 * 256 * 2);
  u16* wdihb = (u16*)alloc(1024 * 392 * 2);
  u16* wdhhb = (u16*)alloc(1024 * 256 * 2);
  u16* w1ab  = (u16*)alloc(256 * 256 * 2);
  u16* w2ab  = (u16*)alloc(256 * 256 * 2);
  u16* wo1b  = (u16*)alloc(128 * 256 * 2);
  float* bsum0 = (float*)alloc(1024 * 4);
  float* bsum1 = (float*)alloc(1024 * 4);
  float* bsumd = (float*)alloc(1024 * 4);

  // ---- batch chunking: per-row scratch = 6452 B; fit chunk into remaining ws ----
  // xbf 36 + y0 1536 + y1 1536 + c 1024 + hdec0 512 + hdec1 512 + qt1 512 + dec_in 784
  const long perRow = 6452;
  long avail = (long)ws_size - (long)off - 16384;  // margin for per-buffer padding
  long R = avail > 0 ? avail / perRow : 64;
  R &= ~63L;
  if (R > BATCH) R = BATCH;
  if (R < 64) R = 64;

  u16* xbf    = (u16*)alloc((size_t)R * 18 * 2);
  u16* y0     = (u16*)alloc((size_t)R * 768 * 2);   // layer0 outputs; later reused for enc_proj
  u16* y1     = (u16*)alloc((size_t)R * 768 * 2);   // layer1 outputs = encoder_outputs
  float* cbuf = (float*)alloc((size_t)R * 256 * 4); // c for layer0, then layer1, then decoder
  u16* hdec0  = (u16*)alloc((size_t)R * 256 * 2);
  u16* hdec1  = (u16*)alloc((size_t)R * 256 * 2);
  u16* qt1    = (u16*)alloc((size_t)R * 256 * 2);   // q then t1 (non-overlapping lifetimes)
  u16* dec_in = (u16*)alloc((size_t)R * 392 * 2);

  auto cvt = [&](const float* s, u16* d, long rows, int scols, int dstride) {
    long n = rows * (long)scols;
    long b = (n + 255) / 256; if (b > 4096) b = 4096;
    cvt_kernel<<<dim3((unsigned)b), dim3(256), 0, stream>>>(s, d, rows, scols, dstride);
  };

  // ---- prep: weight/bias conversion (once per call; deterministic) ----
  cvt(W_ih0, wih0b, 1024, 6, 6);
  cvt(W_hh0, whh0b, 1024, 256, 256);
  cvt(W_ih1, wih1b, 1024, 256, 256);
  cvt(W_hh1, whh1b, 1024, 256, 256);
  cvt(Wd_ih, wdihb, 1024, 390, 392);   // pad stride for 16B-aligned rows
  cvt(Wd_hh, wdhhb, 1024, 256, 256);
  cvt(W1a,   w1ab,  256, 256, 256);
  cvt(W2a,   w2ab,  256, 256, 256);
  cvt(Wo1,   wo1b,  128, 256, 256);
  bias_sum_kernel<<<dim3(4), dim3(256), 0, stream>>>(b_ih0, b_hh0, bsum0, 1024);
  bias_sum_kernel<<<dim3(4), dim3(256), 0, stream>>>(b_ih1, b_hh1, bsum1, 1024);
  bias_sum_kernel<<<dim3(4), dim3(256), 0, stream>>>(bd_ih, bd_hh, bsumd, 1024);

  const dim3 blk(256);

  for (long r0 = 0; r0 < BATCH; r0 += R) {
    const long Rc = (BATCH - r0 < R) ? (BATCH - r0) : R;
    const unsigned rows64 = (unsigned)(Rc / 64);
    const dim3 gcell(rows64, 4);
    const dim3 gfull(rows64, 1);
    const float* cbc_c  = cbc + r0 * 18;
    const float* base_c = base + r0 * 10;
    float* out_c = out + r0 * 30;

    cvt(cbc_c, xbf, Rc * 3, 6, 6);
    baseline_kernel<<<dim3((unsigned)(Rc / 4)), blk, 0, stream>>>(base_c, Wb, bb, ln_g, ln_b, dec_in);
    init_last_kernel<<<dim3((unsigned)((Rc * 6 + 255) / 256)), blk, 0, stream>>>(cbc_c, dec_in, Rc * 6);

    // ---- encoder layer 0 ----
    for (int t = 0; t < 3; ++t) {
      const u16* a2 = t ? (y0 + (t - 1) * 256) : nullptr;
      mfma_gemm<1><<<gcell, blk, 0, stream>>>(
          xbf + t * 6, 18, 6, wih0b, 6,
          a2, 768, 256, whh0b, 256,
          256, 64, 4, bsum0,
          nullptr, 0, 0,
          (t ? cbuf : nullptr), cbuf, y0 + t * 256, 768);
    }
    // ---- encoder layer 1 ----
    for (int t = 0; t < 3; ++t) {
      const u16* a2 = t ? (y1 + (t - 1) * 256) : nullptr;
      mfma_gemm<1><<<gcell, blk, 0, stream>>>(
          y0 + t * 256, 768, 256, wih1b, 256,
          a2, 768, 256, whh1b, 256,
          256, 64, 4, bsum1,
          nullptr, 0, 0,
          (t ? cbuf : nullptr), cbuf, y1 + t * 256, 768);
    }
    // ---- enc_proj = encoder_outputs @ W2a^T + b2a  (into y0, now dead) ----
    mfma_gemm<0><<<dim3(rows64 * 3, 1), blk, 0, stream>>>(
        y1, 256, 256, w2ab, 256,
        nullptr, 0, 0, nullptr, 0,
        64, 0, 4, b2a,
        y0, 256, 0,
        nullptr, nullptr, nullptr, 0);

    // ---- decoder ----
    const u16* hcur = y1 + 2 * 256; int hld = 768;   // hT
    for (int s = 0; s < 5; ++s) {
      // q = h @ W1a^T + b1a
      mfma_gemm<0><<<gfull, blk, 0, stream>>>(
          hcur, hld, 256, w1ab, 256,
          nullptr, 0, 0, nullptr, 0,
          64, 0, 4, b1a,
          qt1, 256, 0,
          nullptr, nullptr, nullptr, 0);
      // attention -> context into dec_in[:, 6:262]
      attn_kernel<<<dim3((unsigned)(Rc / 4)), blk, 0, stream>>>(qt1, y0, y1, va, ba, dec_in);
      // decoder LSTM cell
      u16* hnext = (s & 1) ? hdec1 : hdec0;
      mfma_gemm<1><<<gcell, blk, 0, stream>>>(
          dec_in, 392, 390, wdihb, 392,
          hcur, hld, 256, wdhhb, 256,
          256, 64, 4, bsumd,
          nullptr, 0, 0,
          cbuf, cbuf, hnext, 256);
      hcur = hnext; hld = 256;
      // t1 = relu(h @ Wo1^T + bo1)
      mfma_gemm<0><<<gfull, blk, 0, stream>>>(
          hcur, 256, 256, wo1b, 256,
          nullptr, 0, 0, nullptr, 0,
          64, 0, 2, bo1,
          qt1, 128, 1,
          nullptr, nullptr, nullptr, 0);
      // delta + pred
      const float* lastp = (s == 0) ? (cbc_c + 12) : (out_c + (long)(s - 1) * 6);
      const int lstr = (s == 0) ? 18 : 30;
      delta_kernel<<<dim3(rows64), blk, 0, stream>>>(
          qt1, Wo2, bo2, lastp, lstr, out_c + (long)s * 6, 30, dec_in);
    }
  }
}

// Round 4
// 1078.775 us; speedup vs baseline: 3.5227x; 3.5227x over previous
//
#include <hip/hip_runtime.h>

typedef unsigned short u16;
typedef __bf16 bf16x8 __attribute__((ext_vector_type(8)));
typedef float f32x4 __attribute__((ext_vector_type(4)));

#define BATCH 32768L

__device__ __forceinline__ u16 f2b(float f) {
  union { float f; unsigned int u; } v; v.f = f;
  unsigned int r = v.u + 0x7fffu + ((v.u >> 16) & 1u);
  return (u16)(r >> 16);
}
__device__ __forceinline__ float b2f(u16 h) {
  union { unsigned int u; float f; } v; v.u = ((unsigned int)h) << 16;
  return v.f;
}
__device__ __forceinline__ float sigf(float x) { return 1.f / (1.f + __expf(-x)); }
__device__ __forceinline__ float tanh_f(float x) { return 2.f / (1.f + __expf(-2.f * x)) - 1.f; }

// async global -> LDS, 16B per lane; LDS dest is wave-uniform base + lane*16
__device__ __forceinline__ void gload16(const void* g, void* l) {
  __builtin_amdgcn_global_load_lds((const __attribute__((address_space(1))) unsigned int*)g,
                                   (__attribute__((address_space(3))) unsigned int*)l,
                                   16, 0, 0);
}

// ---------------- f32 -> bf16 convert with zero-padded dst stride ----------------
__global__ void cvt_pad_kernel(const float* __restrict__ src, u16* __restrict__ dst,
                               long rows, int scols, int dstride) {
  long n = rows * (long)dstride;
  for (long i = (long)blockIdx.x * blockDim.x + threadIdx.x; i < n;
       i += (long)gridDim.x * blockDim.x) {
    long r = i / dstride; int c = (int)(i - r * dstride);
    dst[i] = (c < scols) ? f2b(src[r * (long)scols + c]) : (u16)0;
  }
}

__global__ void bias_sum_kernel(const float* __restrict__ a, const float* __restrict__ b,
                                float* __restrict__ o, int n) {
  int i = blockIdx.x * 256 + threadIdx.x;
  if (i < n) o[i] = a[i] + b[i];
}

// last_cbc (cols 0..5) of dec_in; cbc already offset to chunk
__global__ void init_last_kernel(const float* __restrict__ cbc, u16* __restrict__ dec_in, long n) {
  long i = (long)blockIdx.x * 256 + threadIdx.x;
  if (i < n) {
    long r = i / 6; int j = (int)(i - r * 6);
    dec_in[r * 416 + j] = f2b(cbc[r * 18 + 12 + j]);
  }
}

// zero dec_in pad cols 390..415
__global__ void zpad_kernel(u16* __restrict__ dec_in, long n) {
  long i = (long)blockIdx.x * 256 + threadIdx.x;
  if (i < n) {
    long r = i / 26; int j = (int)(i - r * 26);
    dec_in[r * 416 + 390 + j] = 0;
  }
}

// ---------------- MFMA GEMM: C = act(A1@W1^T + A2@W2^T + bias) ----------------
// Block: 128 rows x (NG x 64) cols, 4 waves (wave w owns rows [w*32, w*32+32)).
// K1,K2 multiples of 32; lda/wld even, strides*2 multiple of 16B; rows multiple of 128.
// Double-buffered LDS staged via global_load_lds; one __syncthreads per K-chunk.
// W row for (group g, col c) = g*gs + blockIdx.y*ys + c.
// EPI=0: store bf16 (+bias, optional relu). EPI=1 (NG=4): LSTM gating.
template <int EPI, int NG>
__global__ __launch_bounds__(256, 2)
void mfma_gemm2(const u16* __restrict__ A1, long lda1, int K1,
                const u16* __restrict__ W1, int wld1,
                const u16* __restrict__ A2, long lda2, int K2,
                const u16* __restrict__ W2, int wld2,
                int gs, int ys, const float* __restrict__ bias,
                u16* __restrict__ out0, int ldo, int relu,
                const float* __restrict__ cprev, float* __restrict__ cout,
                u16* __restrict__ hout, int ldh)
{
  __shared__ u16 As[2][128 * 32];        // linear [row][32], 64B rows
  __shared__ u16 Bs[2][NG * 64 * 32];
  const int tid = threadIdx.x;
  const int l = tid & 63, w = tid >> 6;
  const long bm = (long)blockIdx.x * 128;
  const int yb = blockIdx.y;

  const int nch1 = K1 >> 5;
  const int nch2 = A2 ? (K2 >> 5) : 0;
  const int nt = nch1 + nch2;

  f32x4 acc[2][NG][4];
#pragma unroll
  for (int rf = 0; rf < 2; ++rf)
#pragma unroll
    for (int g = 0; g < NG; ++g)
#pragma unroll
      for (int n = 0; n < 4; ++n) acc[rf][g][n] = (f32x4){0.f, 0.f, 0.f, 0.f};

  const int l4q = l >> 2;          // row within 16-row stage slab
  const int l4r = (l & 3) * 16;    // byte offset within 64B row

  auto stage = [&](int ch, int buf) {
    const u16* A; const u16* W; long lda; int wld; int kb;
    if (ch < nch1) { A = A1; W = W1; lda = lda1; wld = wld1; kb = ch << 5; }
    else           { A = A2; W = W2; lda = lda2; wld = wld2; kb = (ch - nch1) << 5; }
#pragma unroll
    for (int c = 0; c < 2; ++c) {
      const int row = w * 32 + c * 16;
      const char* g = (const char*)A + ((bm + row + l4q) * lda + kb) * 2 + l4r;
      gload16(g, &As[buf][row * 32]);
    }
#pragma unroll
    for (int c = 0; c < NG; ++c) {
      const int brow0 = w * (NG * 16) + c * 16;
      const int brow = brow0 + l4q;
      const int gi = brow >> 6, inrow = brow & 63;
      const long wrow = (long)gi * gs + (long)yb * ys + inrow;
      const char* g = (const char*)W + (wrow * wld + kb) * 2 + l4r;
      gload16(g, &Bs[buf][brow0 * 32]);
    }
  };

  stage(0, 0);
  int cur = 0;
  const int koff = (l >> 4) * 8;
  const int rb = l & 15;
  for (int ch = 0; ch < nt; ++ch) {
    __syncthreads();                       // staged loads for buf[cur] complete; prev reads done
    if (ch + 1 < nt) stage(ch + 1, cur ^ 1);
    const u16* Ab = As[cur];
    const u16* Bb = Bs[cur];
    bf16x8 af0 = *(const bf16x8*)&Ab[(w * 32 + rb) * 32 + koff];
    bf16x8 af1 = *(const bf16x8*)&Ab[(w * 32 + 16 + rb) * 32 + koff];
#pragma unroll
    for (int g = 0; g < NG; ++g) {
#pragma unroll
      for (int n = 0; n < 4; ++n) {
        bf16x8 bfr = *(const bf16x8*)&Bb[(g * 64 + n * 16 + rb) * 32 + koff];
        acc[0][g][n] = __builtin_amdgcn_mfma_f32_16x16x32_bf16(af0, bfr, acc[0][g][n], 0, 0, 0);
        acc[1][g][n] = __builtin_amdgcn_mfma_f32_16x16x32_bf16(af1, bfr, acc[1][g][n], 0, 0, 0);
      }
    }
    cur ^= 1;
  }

  const int colb = l & 15;
  const int rq = l >> 4;
  if constexpr (EPI == 0) {
#pragma unroll
    for (int rf = 0; rf < 2; ++rf)
      for (int g = 0; g < NG; ++g)
#pragma unroll
        for (int n = 0; n < 4; ++n) {
          const int wrow = g * gs + yb * ys + n * 16 + colb;
          const float bi = bias[wrow];
#pragma unroll
          for (int r = 0; r < 4; ++r) {
            const long row = bm + w * 32 + rf * 16 + rq * 4 + r;
            float vv = acc[rf][g][n][r] + bi;
            if (relu) vv = fmaxf(vv, 0.f);
            out0[row * (long)ldo + wrow] = f2b(vv);
          }
        }
  } else {
#pragma unroll
    for (int rf = 0; rf < 2; ++rf)
#pragma unroll
      for (int n = 0; n < 4; ++n) {
        const int cb = yb * 64 + n * 16 + colb;
        const float b_i = bias[cb];
        const float b_f = bias[256 + cb];
        const float b_g = bias[512 + cb];
        const float b_o = bias[768 + cb];
#pragma unroll
        for (int r = 0; r < 4; ++r) {
          const long row = bm + w * 32 + rf * 16 + rq * 4 + r;
          const float zi = acc[rf][0][n][r] + b_i;
          const float zf = acc[rf][1][n][r] + b_f;
          const float zg = acc[rf][2][n][r] + b_g;
          const float zo = acc[rf][3][n][r] + b_o;
          const float cp = cprev ? cprev[row * 256 + cb] : 0.f;
          const float cn = sigf(zf) * cp + sigf(zi) * tanh_f(zg);
          const float hn = sigf(zo) * tanh_f(cn);
          cout[row * 256 + cb] = cn;
          hout[row * (long)ldh + cb] = f2b(hn);
        }
      }
  }
}

// ---------------- baseline MLP + LayerNorm -> dec_in[:, 262:390] ----------------
__global__ __launch_bounds__(256)
void baseline_kernel(const float* __restrict__ baseline, const float* __restrict__ Wb,
                     const float* __restrict__ bb, const float* __restrict__ ln_g,
                     const float* __restrict__ ln_b, u16* __restrict__ dec_in)
{
  __shared__ float wbs[1280];
  __shared__ float bbs[128], lgs[128], lbs[128];
  const int tid = threadIdx.x;
  for (int i = tid; i < 1280; i += 256) wbs[i] = Wb[i];
  if (tid < 128) { bbs[tid] = bb[tid]; lgs[tid] = ln_g[tid]; lbs[tid] = ln_b[tid]; }
  __syncthreads();
  const int l = tid & 63, w = tid >> 6;
  const long row = (long)blockIdx.x * 4 + w;
  float bl[10];
#pragma unroll
  for (int k = 0; k < 10; ++k) bl[k] = baseline[row * 10 + k];
  const int c0 = l, c1 = l + 64;
  float z0 = bbs[c0], z1 = bbs[c1];
#pragma unroll
  for (int k = 0; k < 10; ++k) { z0 += bl[k] * wbs[c0 * 10 + k]; z1 += bl[k] * wbs[c1 * 10 + k]; }
  z0 = fmaxf(z0, 0.f); z1 = fmaxf(z1, 0.f);
  float s = z0 + z1, sq = z0 * z0 + z1 * z1;
#pragma unroll
  for (int m = 32; m; m >>= 1) { s += __shfl_xor(s, m); sq += __shfl_xor(sq, m); }
  const float mu = s * (1.f / 128.f);
  const float var = sq * (1.f / 128.f) - mu * mu;
  const float rs = rsqrtf(var + 1e-5f);
  dec_in[row * 416 + 262 + c0] = f2b((z0 - mu) * rs * lgs[c0] + lbs[c0]);
  dec_in[row * 416 + 262 + c1] = f2b((z1 - mu) * rs * lgs[c1] + lbs[c1]);
}

// ---------------- attention: scores -> softmax(3) -> context -> dec_in[:, 6:262] ----------------
__global__ __launch_bounds__(256)
void attn_kernel(const u16* __restrict__ q, const u16* __restrict__ ep,
                 const u16* __restrict__ eo, const float* __restrict__ va,
                 const float* __restrict__ ba, u16* __restrict__ dec_in)
{
  const int tid = threadIdx.x;
  const int l = tid & 63, w = tid >> 6;
  const long row = (long)blockIdx.x * 4 + w;
  const int c = l * 4;
  float qv[4], vav[4];
  {
    ushort4 qu = *(const ushort4*)&q[row * 256 + c];
    qv[0] = b2f(qu.x); qv[1] = b2f(qu.y); qv[2] = b2f(qu.z); qv[3] = b2f(qu.w);
    float4 vv = *(const float4*)&va[c];
    vav[0] = vv.x; vav[1] = vv.y; vav[2] = vv.z; vav[3] = vv.w;
  }
  float s[3];
#pragma unroll
  for (int t = 0; t < 3; ++t) {
    ushort4 eu = *(const ushort4*)&ep[row * 768 + t * 256 + c];
    float p = tanh_f(qv[0] + b2f(eu.x)) * vav[0]
            + tanh_f(qv[1] + b2f(eu.y)) * vav[1]
            + tanh_f(qv[2] + b2f(eu.z)) * vav[2]
            + tanh_f(qv[3] + b2f(eu.w)) * vav[3];
#pragma unroll
    for (int m = 32; m; m >>= 1) p += __shfl_xor(p, m);
    s[t] = p + ba[0];
  }
  const float mx = fmaxf(s[0], fmaxf(s[1], s[2]));
  const float e0 = __expf(s[0] - mx), e1 = __expf(s[1] - mx), e2 = __expf(s[2] - mx);
  const float inv = 1.f / (e0 + e1 + e2);
  const float w0 = e0 * inv, w1 = e1 * inv, w2 = e2 * inv;
  const ushort4 a0 = *(const ushort4*)&eo[row * 768 + 0 * 256 + c];
  const ushort4 a1 = *(const ushort4*)&eo[row * 768 + 1 * 256 + c];
  const ushort4 a2 = *(const ushort4*)&eo[row * 768 + 2 * 256 + c];
  u16* dp = &dec_in[row * 416 + 6 + c];
  dp[0] = f2b(w0 * b2f(a0.x) + w1 * b2f(a1.x) + w2 * b2f(a2.x));
  dp[1] = f2b(w0 * b2f(a0.y) + w1 * b2f(a1.y) + w2 * b2f(a2.y));
  dp[2] = f2b(w0 * b2f(a0.z) + w1 * b2f(a1.z) + w2 * b2f(a2.z));
  dp[3] = f2b(w0 * b2f(a0.w) + w1 * b2f(a1.w) + w2 * b2f(a2.w));
}

// ---------------- output head tail: delta = t1 @ Wo2^T + bo2; pred = last + delta ----------------
__global__ __launch_bounds__(256)
void delta_kernel(const u16* __restrict__ t1, const float* __restrict__ Wo2,
                  const float* __restrict__ bo2, const float* __restrict__ lastp, int lstride,
                  float* __restrict__ outp, int ostride, u16* __restrict__ dec_in)
{
  __shared__ float w2s[768];
  __shared__ float part[64][4][6];
  const int tid = threadIdx.x;
  for (int i = tid; i < 768; i += 256) w2s[i] = Wo2[i];
  __syncthreads();
  const int rw = tid >> 2, q = tid & 3;
  const long row = (long)blockIdx.x * 64 + rw;
  float p[6] = {0.f, 0.f, 0.f, 0.f, 0.f, 0.f};
  const u16* tp = &t1[row * 128 + q * 32];
#pragma unroll
  for (int it = 0; it < 4; ++it) {
    int4 chunk = *(const int4*)&tp[it * 8];
    const u16* cu = (const u16*)&chunk;
#pragma unroll
    for (int e = 0; e < 8; ++e) {
      const float tv = b2f(cu[e]);
      const int k = q * 32 + it * 8 + e;
#pragma unroll
      for (int j = 0; j < 6; ++j) p[j] += tv * w2s[j * 128 + k];
    }
  }
#pragma unroll
  for (int j = 0; j < 6; ++j) part[rw][q][j] = p[j];
  __syncthreads();
  if (tid < 64) {
    const long r2 = (long)blockIdx.x * 64 + tid;
#pragma unroll
    for (int j = 0; j < 6; ++j) {
      const float d = bo2[j] + part[tid][0][j] + part[tid][1][j] + part[tid][2][j] + part[tid][3][j];
      const float pr = lastp[r2 * lstride + j] + d;
      outp[r2 * ostride + j] = pr;
      dec_in[r2 * 416 + j] = f2b(pr);
    }
  }
}

extern "C" void kernel_launch(void* const* d_in, const int* in_sizes, int n_in,
                              void* d_out, int out_size, void* d_ws, size_t ws_size,
                              hipStream_t stream) {
  const float* cbc   = (const float*)d_in[0];
  const float* base  = (const float*)d_in[1];
  const float* W_ih0 = (const float*)d_in[2];
  const float* W_hh0 = (const float*)d_in[3];
  const float* b_ih0 = (const float*)d_in[4];
  const float* b_hh0 = (const float*)d_in[5];
  const float* W_ih1 = (const float*)d_in[6];
  const float* W_hh1 = (const float*)d_in[7];
  const float* b_ih1 = (const float*)d_in[8];
  const float* b_hh1 = (const float*)d_in[9];
  const float* Wb    = (const float*)d_in[10];
  const float* bb    = (const float*)d_in[11];
  const float* ln_g  = (const float*)d_in[12];
  const float* ln_b  = (const float*)d_in[13];
  const float* W1a   = (const float*)d_in[14];
  const float* b1a   = (const float*)d_in[15];
  const float* W2a   = (const float*)d_in[16];
  const float* b2a   = (const float*)d_in[17];
  const float* va    = (const float*)d_in[18];
  const float* ba    = (const float*)d_in[19];
  const float* Wd_ih = (const float*)d_in[20];
  const float* Wd_hh = (const float*)d_in[21];
  const float* bd_ih = (const float*)d_in[22];
  const float* bd_hh = (const float*)d_in[23];
  const float* Wo1   = (const float*)d_in[24];
  const float* bo1   = (const float*)d_in[25];
  const float* Wo2   = (const float*)d_in[26];
  const float* bo2   = (const float*)d_in[27];
  float* out = (float*)d_out;
  (void)in_sizes; (void)n_in; (void)out_size;

  unsigned char* wsb = (unsigned char*)d_ws;
  size_t off = 0;
  auto alloc = [&](size_t bytes) -> void* {
    void* p = wsb + off;
    off += (bytes + 255) & ~(size_t)255;
    return p;
  };
  // ---- persistent (weights, biases) ----
  u16* wih0b = (u16*)alloc(1024 * 32 * 2);    // padded K 6->32
  u16* whh0b = (u16*)alloc(1024 * 256 * 2);
  u16* wih1b = (u16*)alloc(1024 * 256 * 2);
  u16* whh1b = (u16*)alloc(1024 * 256 * 2);
  u16* wdihb = (u16*)alloc(1024 * 416 * 2);   // padded K 390->416
  u16* wdhhb = (u16*)alloc(1024 * 256 * 2);
  u16* w1ab  = (u16*)alloc(256 * 256 * 2);
  u16* w2ab  = (u16*)alloc(256 * 256 * 2);
  u16* wo1b  = (u16*)alloc(128 * 256 * 2);
  float* bsum0 = (float*)alloc(1024 * 4);
  float* bsum1 = (float*)alloc(1024 * 4);
  float* bsumd = (float*)alloc(1024 * 4);

  // ---- batch chunking: per-row bytes ----
  // xbf 3*32*2=192, y0 1536, y1 1536, cbuf 1024, hdec0/1 512+512, qt1 512, dec_in 832
  const long perRow = 6656;
  long avail = (long)ws_size - (long)off - 32768;
  long R = avail > 0 ? avail / perRow : 128;
  R &= ~127L;
  if (R > BATCH) R = BATCH;
  if (R < 128) R = 128;

  u16* xbf    = (u16*)alloc((size_t)R * 96 * 2);    // [R*3][32] padded
  u16* y0     = (u16*)alloc((size_t)R * 768 * 2);   // layer0 outputs; later enc_proj
  u16* y1     = (u16*)alloc((size_t)R * 768 * 2);   // layer1 outputs = encoder_outputs
  float* cbuf = (float*)alloc((size_t)R * 256 * 4); // c: layer0, layer1, decoder
  u16* hdec0  = (u16*)alloc((size_t)R * 256 * 2);
  u16* hdec1  = (u16*)alloc((size_t)R * 256 * 2);
  u16* qt1    = (u16*)alloc((size_t)R * 256 * 2);   // q then t1
  u16* dec_in = (u16*)alloc((size_t)R * 416 * 2);   // [R][416], cols 390..415 zero

  auto cvt = [&](const float* s, u16* d, long rows, int scols, int dstride) {
    long n = rows * (long)dstride;
    long b = (n + 255) / 256; if (b > 4096) b = 4096;
    cvt_pad_kernel<<<dim3((unsigned)b), dim3(256), 0, stream>>>(s, d, rows, scols, dstride);
  };

  // ---- prep: weight/bias conversion ----
  cvt(W_ih0, wih0b, 1024, 6, 32);
  cvt(W_hh0, whh0b, 1024, 256, 256);
  cvt(W_ih1, wih1b, 1024, 256, 256);
  cvt(W_hh1, whh1b, 1024, 256, 256);
  cvt(Wd_ih, wdihb, 1024, 390, 416);
  cvt(Wd_hh, wdhhb, 1024, 256, 256);
  cvt(W1a,   w1ab,  256, 256, 256);
  cvt(W2a,   w2ab,  256, 256, 256);
  cvt(Wo1,   wo1b,  128, 256, 256);
  bias_sum_kernel<<<dim3(4), dim3(256), 0, stream>>>(b_ih0, b_hh0, bsum0, 1024);
  bias_sum_kernel<<<dim3(4), dim3(256), 0, stream>>>(b_ih1, b_hh1, bsum1, 1024);
  bias_sum_kernel<<<dim3(4), dim3(256), 0, stream>>>(bd_ih, bd_hh, bsumd, 1024);

  const dim3 blk(256);

  for (long r0 = 0; r0 < BATCH; r0 += R) {
    const long Rc = (BATCH - r0 < R) ? (BATCH - r0) : R;
    const unsigned nb = (unsigned)(Rc / 128);
    const dim3 gcell(nb, 4);
    const dim3 gfull(nb, 1);
    const float* cbc_c  = cbc + r0 * 18;
    const float* base_c = base + r0 * 10;
    float* out_c = out + r0 * 30;

    cvt(cbc_c, xbf, Rc * 3, 6, 32);
    baseline_kernel<<<dim3((unsigned)(Rc / 4)), blk, 0, stream>>>(base_c, Wb, bb, ln_g, ln_b, dec_in);
    init_last_kernel<<<dim3((unsigned)((Rc * 6 + 255) / 256)), blk, 0, stream>>>(cbc_c, dec_in, Rc * 6);
    zpad_kernel<<<dim3((unsigned)((Rc * 26 + 255) / 256)), blk, 0, stream>>>(dec_in, Rc * 26);

    // ---- encoder layer 0 (K1 padded to 32) ----
    for (int t = 0; t < 3; ++t) {
      const u16* a2 = t ? (y0 + (t - 1) * 256) : nullptr;
      mfma_gemm2<1, 4><<<gcell, blk, 0, stream>>>(
          xbf + t * 32, 96, 32, wih0b, 32,
          a2, 768, 256, whh0b, 256,
          256, 64, bsum0,
          nullptr, 0, 0,
          (t ? cbuf : nullptr), cbuf, y0 + t * 256, 768);
    }
    // ---- encoder layer 1 ----
    for (int t = 0; t < 3; ++t) {
      const u16* a2 = t ? (y1 + (t - 1) * 256) : nullptr;
      mfma_gemm2<1, 4><<<gcell, blk, 0, stream>>>(
          y0 + t * 256, 768, 256, wih1b, 256,
          a2, 768, 256, whh1b, 256,
          256, 64, bsum1,
          nullptr, 0, 0,
          (t ? cbuf : nullptr), cbuf, y1 + t * 256, 768);
    }
    // ---- enc_proj = encoder_outputs @ W2a^T + b2a (into y0, now dead) ----
    mfma_gemm2<0, 4><<<dim3(nb * 3, 1), blk, 0, stream>>>(
        y1, 256, 256, w2ab, 256,
        nullptr, 0, 0, nullptr, 0,
        64, 0, b2a,
        y0, 256, 0,
        nullptr, nullptr, nullptr, 0);

    // ---- decoder ----
    const u16* hcur = y1 + 2 * 256; long hld = 768;   // hT
    for (int s = 0; s < 5; ++s) {
      // q = h @ W1a^T + b1a
      mfma_gemm2<0, 4><<<gfull, blk, 0, stream>>>(
          hcur, hld, 256, w1ab, 256,
          nullptr, 0, 0, nullptr, 0,
          64, 0, b1a,
          qt1, 256, 0,
          nullptr, nullptr, nullptr, 0);
      // attention -> context into dec_in[:, 6:262]
      attn_kernel<<<dim3((unsigned)(Rc / 4)), blk, 0, stream>>>(qt1, y0, y1, va, ba, dec_in);
      // decoder LSTM cell (K1 padded to 416)
      u16* hnext = (s & 1) ? hdec1 : hdec0;
      mfma_gemm2<1, 4><<<gcell, blk, 0, stream>>>(
          dec_in, 416, 416, wdihb, 416,
          hcur, hld, 256, wdhhb, 256,
          256, 64, bsumd,
          nullptr, 0, 0,
          cbuf, cbuf, hnext, 256);
      hcur = hnext; hld = 256;
      // t1 = relu(h @ Wo1^T + bo1)
      mfma_gemm2<0, 2><<<gfull, blk, 0, stream>>>(
          hcur, 256, 256, wo1b, 256,
          nullptr, 0, 0, nullptr, 0,
          64, 0, bo1,
          qt1, 128, 1,
          nullptr, nullptr, nullptr, 0);
      // delta + pred
      const float* lastp = (s == 0) ? (cbc_c + 12) : (out_c + (long)(s - 1) * 6);
      const int lstr = (s == 0) ? 18 : 30;
      delta_kernel<<<dim3((unsigned)(Rc / 64)), blk, 0, stream>>>(
          qt1, Wo2, bo2, lastp, lstr, out_c + (long)s * 6, 30, dec_in);
    }
  }
}

// Round 5
// 1046.006 us; speedup vs baseline: 3.6331x; 1.0313x over previous
//
#include <hip/hip_runtime.h>

typedef unsigned short u16;
typedef __bf16 bf16x8 __attribute__((ext_vector_type(8)));
typedef float f32x4 __attribute__((ext_vector_type(4)));

#define BATCH 32768L

__device__ __forceinline__ u16 f2b(float f) {
  union { float f; unsigned int u; } v; v.f = f;
  unsigned int r = v.u + 0x7fffu + ((v.u >> 16) & 1u);
  return (u16)(r >> 16);
}
__device__ __forceinline__ float b2f(u16 h) {
  union { unsigned int u; float f; } v; v.u = ((unsigned int)h) << 16;
  return v.f;
}
__device__ __forceinline__ float sigf(float x) { return 1.f / (1.f + __expf(-x)); }
__device__ __forceinline__ float tanh_f(float x) { return 2.f / (1.f + __expf(-2.f * x)) - 1.f; }

// async global -> LDS, 16B per lane; LDS dest is wave-uniform base + lane*16
__device__ __forceinline__ void gload16(const void* g, void* l) {
  __builtin_amdgcn_global_load_lds((const __attribute__((address_space(1))) unsigned int*)g,
                                   (__attribute__((address_space(3))) unsigned int*)l,
                                   16, 0, 0);
}

// ---------------- fused prep: 9 weight cvts (f32->bf16, padded) + 3 bias sums ----------------
struct PrepP {
  const float* s[9]; u16* d[9]; int sc[9]; int dc[9]; long n[9];
  const float* ba[3]; const float* bb_[3]; float* bo[3];
};

__global__ void prep_kernel(PrepP p, long cvtTotal, long total) {
  for (long i = (long)blockIdx.x * blockDim.x + threadIdx.x; i < total;
       i += (long)gridDim.x * blockDim.x) {
    if (i < cvtTotal) {
      long off = i; int sg = 0;
      while (off >= p.n[sg]) { off -= p.n[sg]; ++sg; }
      long r = off / p.dc[sg]; int c = (int)(off - r * p.dc[sg]);
      p.d[sg][off] = (c < p.sc[sg]) ? f2b(p.s[sg][r * (long)p.sc[sg] + c]) : (u16)0;
    } else {
      long j = i - cvtTotal; int sg = (int)(j >> 10); int k = (int)(j & 1023);
      p.bo[sg][k] = p.ba[sg][k] + p.bb_[sg][k];
    }
  }
}

// ---------------- f32 -> bf16 convert with zero-padded dst stride ----------------
__global__ void cvt_pad_kernel(const float* __restrict__ src, u16* __restrict__ dst,
                               long rows, int scols, int dstride) {
  long n = rows * (long)dstride;
  for (long i = (long)blockIdx.x * blockDim.x + threadIdx.x; i < n;
       i += (long)gridDim.x * blockDim.x) {
    long r = i / dstride; int c = (int)(i - r * dstride);
    dst[i] = (c < scols) ? f2b(src[r * (long)scols + c]) : (u16)0;
  }
}

// last_cbc (cols 0..5) of dec_in; cbc already offset to chunk
__global__ void init_last_kernel(const float* __restrict__ cbc, u16* __restrict__ dec_in, long n) {
  long i = (long)blockIdx.x * 256 + threadIdx.x;
  if (i < n) {
    long r = i / 6; int j = (int)(i - r * 6);
    dec_in[r * 416 + j] = f2b(cbc[r * 18 + 12 + j]);
  }
}

// zero dec_in pad cols 390..415
__global__ void zpad_kernel(u16* __restrict__ dec_in, long n) {
  long i = (long)blockIdx.x * 256 + threadIdx.x;
  if (i < n) {
    long r = i / 26; int j = (int)(i - r * 26);
    dec_in[r * 416 + 390 + j] = 0;
  }
}

// ---------------- MFMA GEMM: C = act(A1@W1^T + A2@W2^T + bias) ----------------
// Block: 128 rows x (NG x 64) cols, 4 waves. Wave w owns ALL 128 rows x its own
// 16-col sub-frag (n=w) of every 64-col group g -> per chunk: 8 A-frag reads +
// NG B-frag reads per 8*NG MFMAs (43 FLOP/LDS-byte at NG=4).
// K1,K2 multiples of 32; rows multiple of 128; double-buffered LDS via
// global_load_lds with hoisted per-thread pointers (+64B/chunk).
// W row for (group g, col c) = g*gs + blockIdx.y*ys + c.
// EPI=0: store bf16 (+bias, optional relu). EPI=1 (NG=4): LSTM gating.
template <int EPI, int NG>
__global__ __launch_bounds__(256, 2)
void mfma_gemm3(const u16* __restrict__ A1, long lda1, int K1,
                const u16* __restrict__ W1, int wld1,
                const u16* __restrict__ A2, long lda2, int K2,
                const u16* __restrict__ W2, int wld2,
                int gs, int ys, const float* __restrict__ bias,
                u16* __restrict__ out0, int ldo, int relu,
                const float* __restrict__ cprev, float* __restrict__ cout,
                u16* __restrict__ hout, int ldh)
{
  __shared__ u16 As[2][128 * 32];          // linear [row][32], 64B rows
  __shared__ u16 Bs[2][NG * 64 * 32];
  const int tid = threadIdx.x;
  const int l = tid & 63, w = tid >> 6;
  const long bm = (long)blockIdx.x * 128;
  const int yb = blockIdx.y;

  const int nch1 = K1 >> 5;
  const int nch2 = A2 ? (K2 >> 5) : 0;
  const int nt = nch1 + nch2;

  f32x4 acc[8][NG];
#pragma unroll
  for (int rf = 0; rf < 8; ++rf)
#pragma unroll
    for (int g = 0; g < NG; ++g) acc[rf][g] = (f32x4){0.f, 0.f, 0.f, 0.f};

  const int l4q = l >> 2;          // row within 16-row stage slab
  const int l4r = (l & 3) * 16;    // byte offset within 64B row

  const char* pA[2];
  const char* pB[NG];
  auto initA = [&](const u16* A, long lda) {
#pragma unroll
    for (int c = 0; c < 2; ++c)
      pA[c] = (const char*)A + ((bm + w * 32 + c * 16 + l4q) * lda) * 2 + l4r;
  };
  auto initB = [&](const u16* W, int wld) {
#pragma unroll
    for (int c = 0; c < NG; ++c) {
      const int brow = w * (NG * 16) + c * 16 + l4q;
      const long wrow = (long)(brow >> 6) * gs + (long)yb * ys + (brow & 63);
      pB[c] = (const char*)W + (wrow * (long)wld) * 2 + l4r;
    }
  };
  auto stage = [&](int buf) {
#pragma unroll
    for (int c = 0; c < 2; ++c) {
      gload16(pA[c], &As[buf][(w * 32 + c * 16) * 32]);
      pA[c] += 64;
    }
#pragma unroll
    for (int c = 0; c < NG; ++c) {
      gload16(pB[c], &Bs[buf][(w * (NG * 16) + c * 16) * 32]);
      pB[c] += 64;
    }
  };

  initA(A1, lda1);
  initB(W1, wld1);
  stage(0);
  int cur = 0;
  const int koff = (l >> 4) * 8;
  const int rb = l & 15;
  for (int ch = 0; ch < nt; ++ch) {
    if (ch + 1 == nch1 && A2) { initA(A2, lda2); initB(W2, wld2); }
    __syncthreads();                       // buf[cur] staged; prev reads done
    if (ch + 1 < nt) stage(cur ^ 1);
    const u16* Ab = As[cur];
    const u16* Bb = Bs[cur];
    bf16x8 af[8];
#pragma unroll
    for (int rf = 0; rf < 8; ++rf)
      af[rf] = *(const bf16x8*)&Ab[(rf * 16 + rb) * 32 + koff];
#pragma unroll
    for (int g = 0; g < NG; ++g) {
      bf16x8 bfr = *(const bf16x8*)&Bb[(g * 64 + w * 16 + rb) * 32 + koff];
#pragma unroll
      for (int rf = 0; rf < 8; ++rf)
        acc[rf][g] = __builtin_amdgcn_mfma_f32_16x16x32_bf16(af[rf], bfr, acc[rf][g], 0, 0, 0);
    }
    cur ^= 1;
  }

  const int colb = l & 15;
  const int rq = l >> 4;
  if constexpr (EPI == 0) {
#pragma unroll
    for (int g = 0; g < NG; ++g) {
      const int wrow = g * gs + yb * ys + w * 16 + colb;
      const float bi = bias[wrow];
#pragma unroll
      for (int rf = 0; rf < 8; ++rf) {
#pragma unroll
        for (int r = 0; r < 4; ++r) {
          const long row = bm + rf * 16 + rq * 4 + r;
          float vv = acc[rf][g][r] + bi;
          if (relu) vv = fmaxf(vv, 0.f);
          out0[row * (long)ldo + wrow] = f2b(vv);
        }
      }
    }
  } else {
    const int cb = yb * 64 + w * 16 + colb;
    const float b_i = bias[cb];
    const float b_f = bias[256 + cb];
    const float b_g = bias[512 + cb];
    const float b_o = bias[768 + cb];
#pragma unroll
    for (int rf = 0; rf < 8; ++rf) {
#pragma unroll
      for (int r = 0; r < 4; ++r) {
        const long row = bm + rf * 16 + rq * 4 + r;
        const float zi = acc[rf][0][r] + b_i;
        const float zf = acc[rf][1][r] + b_f;
        const float zg = acc[rf][2][r] + b_g;
        const float zo = acc[rf][3][r] + b_o;
        const float cp = cprev ? cprev[row * 256 + cb] : 0.f;
        const float cn = sigf(zf) * cp + sigf(zi) * tanh_f(zg);
        const float hn = sigf(zo) * tanh_f(cn);
        cout[row * 256 + cb] = cn;
        hout[row * (long)ldh + cb] = f2b(hn);
      }
    }
  }
}

// ---------------- baseline MLP + LayerNorm -> dec_in[:, 262:390] ----------------
__global__ __launch_bounds__(256)
void baseline_kernel(const float* __restrict__ baseline, const float* __restrict__ Wb,
                     const float* __restrict__ bb, const float* __restrict__ ln_g,
                     const float* __restrict__ ln_b, u16* __restrict__ dec_in)
{
  __shared__ float wbs[1280];
  __shared__ float bbs[128], lgs[128], lbs[128];
  const int tid = threadIdx.x;
  for (int i = tid; i < 1280; i += 256) wbs[i] = Wb[i];
  if (tid < 128) { bbs[tid] = bb[tid]; lgs[tid] = ln_g[tid]; lbs[tid] = ln_b[tid]; }
  __syncthreads();
  const int l = tid & 63, w = tid >> 6;
  const long row = (long)blockIdx.x * 4 + w;
  float bl[10];
#pragma unroll
  for (int k = 0; k < 10; ++k) bl[k] = baseline[row * 10 + k];
  const int c0 = l, c1 = l + 64;
  float z0 = bbs[c0], z1 = bbs[c1];
#pragma unroll
  for (int k = 0; k < 10; ++k) { z0 += bl[k] * wbs[c0 * 10 + k]; z1 += bl[k] * wbs[c1 * 10 + k]; }
  z0 = fmaxf(z0, 0.f); z1 = fmaxf(z1, 0.f);
  float s = z0 + z1, sq = z0 * z0 + z1 * z1;
#pragma unroll
  for (int m = 32; m; m >>= 1) { s += __shfl_xor(s, m); sq += __shfl_xor(sq, m); }
  const float mu = s * (1.f / 128.f);
  const float var = sq * (1.f / 128.f) - mu * mu;
  const float rs = rsqrtf(var + 1e-5f);
  dec_in[row * 416 + 262 + c0] = f2b((z0 - mu) * rs * lgs[c0] + lbs[c0]);
  dec_in[row * 416 + 262 + c1] = f2b((z1 - mu) * rs * lgs[c1] + lbs[c1]);
}

// ---------------- attention: scores -> softmax(3) -> context -> dec_in[:, 6:262] ----------------
__global__ __launch_bounds__(256)
void attn_kernel(const u16* __restrict__ q, const u16* __restrict__ ep,
                 const u16* __restrict__ eo, const float* __restrict__ va,
                 const float* __restrict__ ba, u16* __restrict__ dec_in)
{
  const int tid = threadIdx.x;
  const int l = tid & 63, w = tid >> 6;
  const long row = (long)blockIdx.x * 4 + w;
  const int c = l * 4;
  float qv[4], vav[4];
  {
    ushort4 qu = *(const ushort4*)&q[row * 256 + c];
    qv[0] = b2f(qu.x); qv[1] = b2f(qu.y); qv[2] = b2f(qu.z); qv[3] = b2f(qu.w);
    float4 vv = *(const float4*)&va[c];
    vav[0] = vv.x; vav[1] = vv.y; vav[2] = vv.z; vav[3] = vv.w;
  }
  float s[3];
#pragma unroll
  for (int t = 0; t < 3; ++t) {
    ushort4 eu = *(const ushort4*)&ep[row * 768 + t * 256 + c];
    float p = tanh_f(qv[0] + b2f(eu.x)) * vav[0]
            + tanh_f(qv[1] + b2f(eu.y)) * vav[1]
            + tanh_f(qv[2] + b2f(eu.z)) * vav[2]
            + tanh_f(qv[3] + b2f(eu.w)) * vav[3];
#pragma unroll
    for (int m = 32; m; m >>= 1) p += __shfl_xor(p, m);
    s[t] = p + ba[0];
  }
  const float mx = fmaxf(s[0], fmaxf(s[1], s[2]));
  const float e0 = __expf(s[0] - mx), e1 = __expf(s[1] - mx), e2 = __expf(s[2] - mx);
  const float inv = 1.f / (e0 + e1 + e2);
  const float w0 = e0 * inv, w1 = e1 * inv, w2 = e2 * inv;
  const ushort4 a0 = *(const ushort4*)&eo[row * 768 + 0 * 256 + c];
  const ushort4 a1 = *(const ushort4*)&eo[row * 768 + 1 * 256 + c];
  const ushort4 a2 = *(const ushort4*)&eo[row * 768 + 2 * 256 + c];
  u16* dp = &dec_in[row * 416 + 6 + c];
  dp[0] = f2b(w0 * b2f(a0.x) + w1 * b2f(a1.x) + w2 * b2f(a2.x));
  dp[1] = f2b(w0 * b2f(a0.y) + w1 * b2f(a1.y) + w2 * b2f(a2.y));
  dp[2] = f2b(w0 * b2f(a0.z) + w1 * b2f(a1.z) + w2 * b2f(a2.z));
  dp[3] = f2b(w0 * b2f(a0.w) + w1 * b2f(a1.w) + w2 * b2f(a2.w));
}

// ---------------- output head tail: delta = t1 @ Wo2^T + bo2; pred = last + delta ----------------
__global__ __launch_bounds__(256)
void delta_kernel(const u16* __restrict__ t1, const float* __restrict__ Wo2,
                  const float* __restrict__ bo2, const float* __restrict__ lastp, int lstride,
                  float* __restrict__ outp, int ostride, u16* __restrict__ dec_in)
{
  __shared__ float w2s[768];
  __shared__ float part[64][4][6];
  const int tid = threadIdx.x;
  for (int i = tid; i < 768; i += 256) w2s[i] = Wo2[i];
  __syncthreads();
  const int rw = tid >> 2, q = tid & 3;
  const long row = (long)blockIdx.x * 64 + rw;
  float p[6] = {0.f, 0.f, 0.f, 0.f, 0.f, 0.f};
  const u16* tp = &t1[row * 128 + q * 32];
#pragma unroll
  for (int it = 0; it < 4; ++it) {
    int4 chunk = *(const int4*)&tp[it * 8];
    const u16* cu = (const u16*)&chunk;
#pragma unroll
    for (int e = 0; e < 8; ++e) {
      const float tv = b2f(cu[e]);
      const int k = q * 32 + it * 8 + e;
#pragma unroll
      for (int j = 0; j < 6; ++j) p[j] += tv * w2s[j * 128 + k];
    }
  }
#pragma unroll
  for (int j = 0; j < 6; ++j) part[rw][q][j] = p[j];
  __syncthreads();
  if (tid < 64) {
    const long r2 = (long)blockIdx.x * 64 + tid;
#pragma unroll
    for (int j = 0; j < 6; ++j) {
      const float d = bo2[j] + part[tid][0][j] + part[tid][1][j] + part[tid][2][j] + part[tid][3][j];
      const float pr = lastp[r2 * lstride + j] + d;
      outp[r2 * ostride + j] = pr;
      dec_in[r2 * 416 + j] = f2b(pr);
    }
  }
}

extern "C" void kernel_launch(void* const* d_in, const int* in_sizes, int n_in,
                              void* d_out, int out_size, void* d_ws, size_t ws_size,
                              hipStream_t stream) {
  const float* cbc   = (const float*)d_in[0];
  const float* base  = (const float*)d_in[1];
  const float* W_ih0 = (const float*)d_in[2];
  const float* W_hh0 = (const float*)d_in[3];
  const float* b_ih0 = (const float*)d_in[4];
  const float* b_hh0 = (const float*)d_in[5];
  const float* W_ih1 = (const float*)d_in[6];
  const float* W_hh1 = (const float*)d_in[7];
  const float* b_ih1 = (const float*)d_in[8];
  const float* b_hh1 = (const float*)d_in[9];
  const float* Wb    = (const float*)d_in[10];
  const float* bb    = (const float*)d_in[11];
  const float* ln_g  = (const float*)d_in[12];
  const float* ln_b  = (const float*)d_in[13];
  const float* W1a   = (const float*)d_in[14];
  const float* b1a   = (const float*)d_in[15];
  const float* W2a   = (const float*)d_in[16];
  const float* b2a   = (const float*)d_in[17];
  const float* va    = (const float*)d_in[18];
  const float* ba    = (const float*)d_in[19];
  const float* Wd_ih = (const float*)d_in[20];
  const float* Wd_hh = (const float*)d_in[21];
  const float* bd_ih = (const float*)d_in[22];
  const float* bd_hh = (const float*)d_in[23];
  const float* Wo1   = (const float*)d_in[24];
  const float* bo1   = (const float*)d_in[25];
  const float* Wo2   = (const float*)d_in[26];
  const float* bo2   = (const float*)d_in[27];
  float* out = (float*)d_out;
  (void)in_sizes; (void)n_in; (void)out_size;

  unsigned char* wsb = (unsigned char*)d_ws;
  size_t off = 0;
  auto alloc = [&](size_t bytes) -> void* {
    void* p = wsb + off;
    off += (bytes + 255) & ~(size_t)255;
    return p;
  };
  // ---- persistent (weights, biases) ----
  u16* wih0b = (u16*)alloc(1024 * 32 * 2);    // padded K 6->32
  u16* whh0b = (u16*)alloc(1024 * 256 * 2);
  u16* wih1b = (u16*)alloc(1024 * 256 * 2);
  u16* whh1b = (u16*)alloc(1024 * 256 * 2);
  u16* wdihb = (u16*)alloc(1024 * 416 * 2);   // padded K 390->416
  u16* wdhhb = (u16*)alloc(1024 * 256 * 2);
  u16* w1ab  = (u16*)alloc(256 * 256 * 2);
  u16* w2ab  = (u16*)alloc(256 * 256 * 2);
  u16* wo1b  = (u16*)alloc(128 * 256 * 2);
  float* bsum0 = (float*)alloc(1024 * 4);
  float* bsum1 = (float*)alloc(1024 * 4);
  float* bsumd = (float*)alloc(1024 * 4);

  // ---- batch chunking: per-row bytes ----
  const long perRow = 6656;
  long avail = (long)ws_size - (long)off - 32768;
  long R = avail > 0 ? avail / perRow : 128;
  R &= ~127L;
  if (R > BATCH) R = BATCH;
  if (R < 128) R = 128;

  u16* xbf    = (u16*)alloc((size_t)R * 96 * 2);    // [R*3][32] padded
  u16* y0     = (u16*)alloc((size_t)R * 768 * 2);   // layer0 outputs; later enc_proj
  u16* y1     = (u16*)alloc((size_t)R * 768 * 2);   // layer1 outputs = encoder_outputs
  float* cbuf = (float*)alloc((size_t)R * 256 * 4); // c: layer0, layer1, decoder
  u16* hdec0  = (u16*)alloc((size_t)R * 256 * 2);
  u16* hdec1  = (u16*)alloc((size_t)R * 256 * 2);
  u16* qt1    = (u16*)alloc((size_t)R * 256 * 2);   // q then t1
  u16* dec_in = (u16*)alloc((size_t)R * 416 * 2);   // [R][416], cols 390..415 zero

  // ---- fused prep (single launch) ----
  {
    PrepP p;
    const float* ss[9] = {W_ih0, W_hh0, W_ih1, W_hh1, Wd_ih, Wd_hh, W1a, W2a, Wo1};
    u16* dd[9]         = {wih0b, whh0b, wih1b, whh1b, wdihb, wdhhb, w1ab, w2ab, wo1b};
    int scv[9]         = {6, 256, 256, 256, 390, 256, 256, 256, 256};
    int dcv[9]         = {32, 256, 256, 256, 416, 256, 256, 256, 256};
    long rows[9]       = {1024, 1024, 1024, 1024, 1024, 1024, 256, 256, 128};
    long cvtTotal = 0;
    for (int i = 0; i < 9; ++i) {
      p.s[i] = ss[i]; p.d[i] = dd[i]; p.sc[i] = scv[i]; p.dc[i] = dcv[i];
      p.n[i] = rows[i] * dcv[i]; cvtTotal += p.n[i];
    }
    p.ba[0] = b_ih0; p.bb_[0] = b_hh0; p.bo[0] = bsum0;
    p.ba[1] = b_ih1; p.bb_[1] = b_hh1; p.bo[1] = bsum1;
    p.ba[2] = bd_ih; p.bb_[2] = bd_hh; p.bo[2] = bsumd;
    prep_kernel<<<dim3(2048), dim3(256), 0, stream>>>(p, cvtTotal, cvtTotal + 3072);
  }

  const dim3 blk(256);

  for (long r0 = 0; r0 < BATCH; r0 += R) {
    const long Rc = (BATCH - r0 < R) ? (BATCH - r0) : R;
    const unsigned nb = (unsigned)(Rc / 128);
    const dim3 gcell(nb, 4);
    const dim3 gfull(nb, 1);
    const float* cbc_c  = cbc + r0 * 18;
    const float* base_c = base + r0 * 10;
    float* out_c = out + r0 * 30;

    {
      long n = Rc * 3 * 32;
      long b = (n + 255) / 256; if (b > 4096) b = 4096;
      cvt_pad_kernel<<<dim3((unsigned)b), blk, 0, stream>>>(cbc_c, xbf, Rc * 3, 6, 32);
    }
    baseline_kernel<<<dim3((unsigned)(Rc / 4)), blk, 0, stream>>>(base_c, Wb, bb, ln_g, ln_b, dec_in);
    init_last_kernel<<<dim3((unsigned)((Rc * 6 + 255) / 256)), blk, 0, stream>>>(cbc_c, dec_in, Rc * 6);
    zpad_kernel<<<dim3((unsigned)((Rc * 26 + 255) / 256)), blk, 0, stream>>>(dec_in, Rc * 26);

    // ---- encoder layer 0 (K1 padded to 32) ----
    for (int t = 0; t < 3; ++t) {
      const u16* a2 = t ? (y0 + (t - 1) * 256) : nullptr;
      mfma_gemm3<1, 4><<<gcell, blk, 0, stream>>>(
          xbf + t * 32, 96, 32, wih0b, 32,
          a2, 768, 256, whh0b, 256,
          256, 64, bsum0,
          nullptr, 0, 0,
          (t ? cbuf : nullptr), cbuf, y0 + t * 256, 768);
    }
    // ---- encoder layer 1 ----
    for (int t = 0; t < 3; ++t) {
      const u16* a2 = t ? (y1 + (t - 1) * 256) : nullptr;
      mfma_gemm3<1, 4><<<gcell, blk, 0, stream>>>(
          y0 + t * 256, 768, 256, wih1b, 256,
          a2, 768, 256, whh1b, 256,
          256, 64, bsum1,
          nullptr, 0, 0,
          (t ? cbuf : nullptr), cbuf, y1 + t * 256, 768);
    }
    // ---- enc_proj = encoder_outputs @ W2a^T + b2a (into y0, now dead) ----
    mfma_gemm3<0, 4><<<dim3(nb * 3, 1), blk, 0, stream>>>(
        y1, 256, 256, w2ab, 256,
        nullptr, 0, 0, nullptr, 0,
        64, 0, b2a,
        y0, 256, 0,
        nullptr, nullptr, nullptr, 0);

    // ---- decoder ----
    const u16* hcur = y1 + 2 * 256; long hld = 768;   // hT
    for (int s = 0; s < 5; ++s) {
      // q = h @ W1a^T + b1a
      mfma_gemm3<0, 4><<<gfull, blk, 0, stream>>>(
          hcur, hld, 256, w1ab, 256,
          nullptr, 0, 0, nullptr, 0,
          64, 0, b1a,
          qt1, 256, 0,
          nullptr, nullptr, nullptr, 0);
      // attention -> context into dec_in[:, 6:262]
      attn_kernel<<<dim3((unsigned)(Rc / 4)), blk, 0, stream>>>(qt1, y0, y1, va, ba, dec_in);
      // decoder LSTM cell (K1 padded to 416)
      u16* hnext = (s & 1) ? hdec1 : hdec0;
      mfma_gemm3<1, 4><<<gcell, blk, 0, stream>>>(
          dec_in, 416, 416, wdihb, 416,
          hcur, hld, 256, wdhhb, 256,
          256, 64, bsumd,
          nullptr, 0, 0,
          cbuf, cbuf, hnext, 256);
      hcur = hnext; hld = 256;
      // t1 = relu(h @ Wo1^T + bo1)
      mfma_gemm3<0, 2><<<gfull, blk, 0, stream>>>(
          hcur, 256, 256, wo1b, 256,
          nullptr, 0, 0, nullptr, 0,
          64, 0, bo1,
          qt1, 128, 1,
          nullptr, nullptr, nullptr, 0);
      // delta + pred
      const float* lastp = (s == 0) ? (cbc_c + 12) : (out_c + (long)(s - 1) * 6);
      const int lstr = (s == 0) ? 18 : 30;
      delta_kernel<<<dim3((unsigned)(Rc / 64)), blk, 0, stream>>>(
          qt1, Wo2, bo2, lastp, lstr, out_c + (long)s * 6, 30, dec_in);
    }
  }
}

// Round 6
// 1038.027 us; speedup vs baseline: 3.6610x; 1.0077x over previous
//
#include <hip/hip_runtime.h>

typedef unsigned short u16;
typedef __bf16 bf16x8 __attribute__((ext_vector_type(8)));
typedef float f32x4 __attribute__((ext_vector_type(4)));

#define BATCH 32768L

__device__ __forceinline__ u16 f2b(float f) {
  union { float f; unsigned int u; } v; v.f = f;
  unsigned int r = v.u + 0x7fffu + ((v.u >> 16) & 1u);
  return (u16)(r >> 16);
}
__device__ __forceinline__ float b2f(u16 h) {
  union { unsigned int u; float f; } v; v.u = ((unsigned int)h) << 16;
  return v.f;
}
__device__ __forceinline__ float sigf(float x) { return 1.f / (1.f + __expf(-x)); }
__device__ __forceinline__ float tanh_f(float x) { return 2.f / (1.f + __expf(-2.f * x)) - 1.f; }

// async global -> LDS, 16B per lane; LDS dest is wave-uniform base + lane*16
__device__ __forceinline__ void gload16(const void* g, void* l) {
  __builtin_amdgcn_global_load_lds((const __attribute__((address_space(1))) unsigned int*)g,
                                   (__attribute__((address_space(3))) unsigned int*)l,
                                   16, 0, 0);
}

// ---------------- fused prep: 9 weight cvts (f32->bf16, padded) + 3 bias sums ----------------
struct PrepP {
  const float* s[9]; u16* d[9]; int sc[9]; int dc[9]; long n[9];
  const float* ba[3]; const float* bb_[3]; float* bo[3];
};

__global__ void prep_kernel(PrepP p, long cvtTotal, long total) {
  for (long i = (long)blockIdx.x * blockDim.x + threadIdx.x; i < total;
       i += (long)gridDim.x * blockDim.x) {
    if (i < cvtTotal) {
      long off = i; int sg = 0;
      while (off >= p.n[sg]) { off -= p.n[sg]; ++sg; }
      long r = off / p.dc[sg]; int c = (int)(off - r * p.dc[sg]);
      p.d[sg][off] = (c < p.sc[sg]) ? f2b(p.s[sg][r * (long)p.sc[sg] + c]) : (u16)0;
    } else {
      long j = i - cvtTotal; int sg = (int)(j >> 10); int k = (int)(j & 1023);
      p.bo[sg][k] = p.ba[sg][k] + p.bb_[sg][k];
    }
  }
}

// ---------------- MFMA GEMM: C = act(A1@W1^T + A2@W2^T + bias) ----------------
// Block: 128 rows x (NG x 64) cols, 4 waves. Wave w owns ALL 128 rows x its own
// 16-col sub-frag of every 64-col group g.
// 3-buffer LDS pipeline, prefetch distance 2, counted s_waitcnt vmcnt(2+NG)
// (never 0 in steady state) + raw s_barrier: one barrier per 32-K chunk.
// XOR-swizzled 16B units: stage source unit = (l&3)^((l>>2)&3) (global layout
// unchanged, per-lane source address permuted within each 64B row-chunk);
// fragment reads use unit (l>>4)^(l&3) -> <=2-way bank aliasing (free).
// K1,K2 multiples of 32; rows multiple of 128.
// W row for (group g, col c) = g*gs + blockIdx.y*ys + c.
// EPI=0: store bf16 (+bias, optional relu). EPI=1 (NG=4): LSTM gating.
template <int EPI, int NG>
__global__ __launch_bounds__(256, 2)
void mfma_gemm4(const u16* __restrict__ A1, long lda1, int K1,
                const u16* __restrict__ W1, int wld1,
                const u16* __restrict__ A2, long lda2, int K2,
                const u16* __restrict__ W2, int wld2,
                int gs, int ys, const float* __restrict__ bias,
                u16* __restrict__ out0, int ldo, int relu,
                const float* __restrict__ cprev, float* __restrict__ cout,
                u16* __restrict__ hout, int ldh)
{
  __shared__ u16 As[3][128 * 32];          // [row][32], 64B rows, swizzled units
  __shared__ u16 Bs[3][NG * 64 * 32];
  const int tid = threadIdx.x;
  const int l = tid & 63, w = tid >> 6;
  const long bm = (long)blockIdx.x * 128;
  const int yb = blockIdx.y;

  const int nch1 = K1 >> 5;
  const int nch2 = A2 ? (K2 >> 5) : 0;
  const int nt = nch1 + nch2;

  f32x4 acc[8][NG];
#pragma unroll
  for (int rf = 0; rf < 8; ++rf)
#pragma unroll
    for (int g = 0; g < NG; ++g) acc[rf][g] = (f32x4){0.f, 0.f, 0.f, 0.f};

  const int l4q = l >> 2;                            // row within 16-row slab
  const int swzs = ((l & 3) ^ ((l >> 2) & 3)) * 16;  // staging source byte offset

  const char* pA[2];
  const char* pB[NG];
  auto initA = [&](const u16* A, long lda) {
#pragma unroll
    for (int c = 0; c < 2; ++c)
      pA[c] = (const char*)A + ((bm + w * 32 + c * 16 + l4q) * lda) * 2 + swzs;
  };
  auto initB = [&](const u16* W, int wld) {
#pragma unroll
    for (int c = 0; c < NG; ++c) {
      const int brow = w * (NG * 16) + c * 16 + l4q;
      const long wrow = (long)(brow >> 6) * gs + (long)yb * ys + (brow & 63);
      pB[c] = (const char*)W + (wrow * (long)wld) * 2 + swzs;
    }
  };
  auto stage = [&](int buf) {
#pragma unroll
    for (int c = 0; c < 2; ++c) {
      gload16(pA[c], &As[buf][(w * 32 + c * 16) * 32]);
      pA[c] += 64;
    }
#pragma unroll
    for (int c = 0; c < NG; ++c) {
      gload16(pB[c], &Bs[buf][(w * (NG * 16) + c * 16) * 32]);
      pB[c] += 64;
    }
  };

  initA(A1, lda1);
  initB(W1, wld1);
  stage(0);
  if (A2 && nch1 == 1) { initA(A2, lda2); initB(W2, wld2); }
  if (nt > 1) stage(1);

  const int rb = l & 15;
  const int koff = ((l >> 4) ^ (l & 3)) * 8;   // swizzled 16B-unit read offset
  int bufR = 0, bufS = 2;
  for (int ch = 0; ch < nt; ++ch) {
    if (ch + 1 < nt) {
      asm volatile("s_waitcnt vmcnt(%0)\n\ts_barrier" :: "i"(2 + NG) : "memory");
    } else {
      asm volatile("s_waitcnt vmcnt(0)\n\ts_barrier" ::: "memory");
    }
    const int s = ch + 2;
    if (s < nt) {
      if (A2 && s == nch1) { initA(A2, lda2); initB(W2, wld2); }
      stage(bufS);
    }
    const u16* Ab = As[bufR];
    const u16* Bb = Bs[bufR];
    bf16x8 af[8];
#pragma unroll
    for (int rf = 0; rf < 8; ++rf)
      af[rf] = *(const bf16x8*)&Ab[(rf * 16 + rb) * 32 + koff];
#pragma unroll
    for (int g = 0; g < NG; ++g) {
      bf16x8 bfr = *(const bf16x8*)&Bb[(g * 64 + w * 16 + rb) * 32 + koff];
#pragma unroll
      for (int rf = 0; rf < 8; ++rf)
        acc[rf][g] = __builtin_amdgcn_mfma_f32_16x16x32_bf16(af[rf], bfr, acc[rf][g], 0, 0, 0);
    }
    bufR = (bufR == 2) ? 0 : bufR + 1;
    bufS = (bufS == 2) ? 0 : bufS + 1;
  }

  const int colb = l & 15;
  const int rq = l >> 4;
  if constexpr (EPI == 0) {
#pragma unroll
    for (int g = 0; g < NG; ++g) {
      const int wrow = g * gs + yb * ys + w * 16 + colb;
      const float bi = bias[wrow];
#pragma unroll
      for (int rf = 0; rf < 8; ++rf) {
#pragma unroll
        for (int r = 0; r < 4; ++r) {
          const long row = bm + rf * 16 + rq * 4 + r;
          float vv = acc[rf][g][r] + bi;
          if (relu) vv = fmaxf(vv, 0.f);
          out0[row * (long)ldo + wrow] = f2b(vv);
        }
      }
    }
  } else {
    const int cb = yb * 64 + w * 16 + colb;
    const float b_i = bias[cb];
    const float b_f = bias[256 + cb];
    const float b_g = bias[512 + cb];
    const float b_o = bias[768 + cb];
#pragma unroll
    for (int rf = 0; rf < 8; ++rf) {
#pragma unroll
      for (int r = 0; r < 4; ++r) {
        const long row = bm + rf * 16 + rq * 4 + r;
        const float zi = acc[rf][0][r] + b_i;
        const float zf = acc[rf][1][r] + b_f;
        const float zg = acc[rf][2][r] + b_g;
        const float zo = acc[rf][3][r] + b_o;
        const float cp = cprev ? cprev[row * 256 + cb] : 0.f;
        const float cn = sigf(zf) * cp + sigf(zi) * tanh_f(zg);
        const float hn = sigf(zo) * tanh_f(cn);
        cout[row * 256 + cb] = cn;
        hout[row * (long)ldh + cb] = f2b(hn);
      }
    }
  }
}

// ---------------- fused front: baseline MLP+LN, last_cbc, zpad, xbf cvt ----------------
__global__ __launch_bounds__(256)
void front_kernel(const float* __restrict__ cbc, const float* __restrict__ baseline,
                  const float* __restrict__ Wb, const float* __restrict__ bb,
                  const float* __restrict__ ln_g, const float* __restrict__ ln_b,
                  u16* __restrict__ dec_in, u16* __restrict__ xbf)
{
  __shared__ float wbs[1280];
  __shared__ float bbs[128], lgs[128], lbs[128];
  const int tid = threadIdx.x;
  for (int i = tid; i < 1280; i += 256) wbs[i] = Wb[i];
  if (tid < 128) { bbs[tid] = bb[tid]; lgs[tid] = ln_g[tid]; lbs[tid] = ln_b[tid]; }
  __syncthreads();
  const int l = tid & 63, w = tid >> 6;
  const long row = (long)blockIdx.x * 4 + w;
  // xbf: [row*3+t][32], cols >=6 zero
#pragma unroll
  for (int e = l; e < 96; e += 64) {
    const int t = e >> 5, c = e & 31;
    xbf[(row * 3 + t) * 32 + c] = (c < 6) ? f2b(cbc[row * 18 + t * 6 + c]) : (u16)0;
  }
  // last_cbc cols 0..5; pad cols 390..415
  if (l < 6) dec_in[row * 416 + l] = f2b(cbc[row * 18 + 12 + l]);
  else if (l < 32) dec_in[row * 416 + 390 + (l - 6)] = 0;
  // baseline MLP + LayerNorm -> cols 262..389
  float bl[10];
#pragma unroll
  for (int k = 0; k < 10; ++k) bl[k] = baseline[row * 10 + k];
  const int c0 = l, c1 = l + 64;
  float z0 = bbs[c0], z1 = bbs[c1];
#pragma unroll
  for (int k = 0; k < 10; ++k) { z0 += bl[k] * wbs[c0 * 10 + k]; z1 += bl[k] * wbs[c1 * 10 + k]; }
  z0 = fmaxf(z0, 0.f); z1 = fmaxf(z1, 0.f);
  float s = z0 + z1, sq = z0 * z0 + z1 * z1;
#pragma unroll
  for (int m = 32; m; m >>= 1) { s += __shfl_xor(s, m); sq += __shfl_xor(sq, m); }
  const float mu = s * (1.f / 128.f);
  const float var = sq * (1.f / 128.f) - mu * mu;
  const float rs = rsqrtf(var + 1e-5f);
  dec_in[row * 416 + 262 + c0] = f2b((z0 - mu) * rs * lgs[c0] + lbs[c0]);
  dec_in[row * 416 + 262 + c1] = f2b((z1 - mu) * rs * lgs[c1] + lbs[c1]);
}

// ---------------- attention: scores -> softmax(3) -> context -> dec_in[:, 6:262] ----------------
__global__ __launch_bounds__(256)
void attn_kernel(const u16* __restrict__ q, const u16* __restrict__ ep,
                 const u16* __restrict__ eo, const float* __restrict__ va,
                 const float* __restrict__ ba, u16* __restrict__ dec_in)
{
  const int tid = threadIdx.x;
  const int l = tid & 63, w = tid >> 6;
  const long row = (long)blockIdx.x * 4 + w;
  const int c = l * 4;
  float qv[4], vav[4];
  {
    ushort4 qu = *(const ushort4*)&q[row * 256 + c];
    qv[0] = b2f(qu.x); qv[1] = b2f(qu.y); qv[2] = b2f(qu.z); qv[3] = b2f(qu.w);
    float4 vv = *(const float4*)&va[c];
    vav[0] = vv.x; vav[1] = vv.y; vav[2] = vv.z; vav[3] = vv.w;
  }
  float s[3];
#pragma unroll
  for (int t = 0; t < 3; ++t) {
    ushort4 eu = *(const ushort4*)&ep[row * 768 + t * 256 + c];
    float p = tanh_f(qv[0] + b2f(eu.x)) * vav[0]
            + tanh_f(qv[1] + b2f(eu.y)) * vav[1]
            + tanh_f(qv[2] + b2f(eu.z)) * vav[2]
            + tanh_f(qv[3] + b2f(eu.w)) * vav[3];
#pragma unroll
    for (int m = 32; m; m >>= 1) p += __shfl_xor(p, m);
    s[t] = p + ba[0];
  }
  const float mx = fmaxf(s[0], fmaxf(s[1], s[2]));
  const float e0 = __expf(s[0] - mx), e1 = __expf(s[1] - mx), e2 = __expf(s[2] - mx);
  const float inv = 1.f / (e0 + e1 + e2);
  const float w0 = e0 * inv, w1 = e1 * inv, w2 = e2 * inv;
  const ushort4 a0 = *(const ushort4*)&eo[row * 768 + 0 * 256 + c];
  const ushort4 a1 = *(const ushort4*)&eo[row * 768 + 1 * 256 + c];
  const ushort4 a2 = *(const ushort4*)&eo[row * 768 + 2 * 256 + c];
  u16* dp = &dec_in[row * 416 + 6 + c];
  dp[0] = f2b(w0 * b2f(a0.x) + w1 * b2f(a1.x) + w2 * b2f(a2.x));
  dp[1] = f2b(w0 * b2f(a0.y) + w1 * b2f(a1.y) + w2 * b2f(a2.y));
  dp[2] = f2b(w0 * b2f(a0.z) + w1 * b2f(a1.z) + w2 * b2f(a2.z));
  dp[3] = f2b(w0 * b2f(a0.w) + w1 * b2f(a1.w) + w2 * b2f(a2.w));
}

// ---------------- output head tail: delta = t1 @ Wo2^T + bo2; pred = last + delta ----------------
__global__ __launch_bounds__(256)
void delta_kernel(const u16* __restrict__ t1, const float* __restrict__ Wo2,
                  const float* __restrict__ bo2, const float* __restrict__ lastp, int lstride,
                  float* __restrict__ outp, int ostride, u16* __restrict__ dec_in)
{
  __shared__ float w2s[768];
  __shared__ float part[64][4][6];
  const int tid = threadIdx.x;
  for (int i = tid; i < 768; i += 256) w2s[i] = Wo2[i];
  __syncthreads();
  const int rw = tid >> 2, q = tid & 3;
  const long row = (long)blockIdx.x * 64 + rw;
  float p[6] = {0.f, 0.f, 0.f, 0.f, 0.f, 0.f};
  const u16* tp = &t1[row * 128 + q * 32];
#pragma unroll
  for (int it = 0; it < 4; ++it) {
    int4 chunk = *(const int4*)&tp[it * 8];
    const u16* cu = (const u16*)&chunk;
#pragma unroll
    for (int e = 0; e < 8; ++e) {
      const float tv = b2f(cu[e]);
      const int k = q * 32 + it * 8 + e;
#pragma unroll
      for (int j = 0; j < 6; ++j) p[j] += tv * w2s[j * 128 + k];
    }
  }
#pragma unroll
  for (int j = 0; j < 6; ++j) part[rw][q][j] = p[j];
  __syncthreads();
  if (tid < 64) {
    const long r2 = (long)blockIdx.x * 64 + tid;
#pragma unroll
    for (int j = 0; j < 6; ++j) {
      const float d = bo2[j] + part[tid][0][j] + part[tid][1][j] + part[tid][2][j] + part[tid][3][j];
      const float pr = lastp[r2 * lstride + j] + d;
      outp[r2 * ostride + j] = pr;
      dec_in[r2 * 416 + j] = f2b(pr);
    }
  }
}

extern "C" void kernel_launch(void* const* d_in, const int* in_sizes, int n_in,
                              void* d_out, int out_size, void* d_ws, size_t ws_size,
                              hipStream_t stream) {
  const float* cbc   = (const float*)d_in[0];
  const float* base  = (const float*)d_in[1];
  const float* W_ih0 = (const float*)d_in[2];
  const float* W_hh0 = (const float*)d_in[3];
  const float* b_ih0 = (const float*)d_in[4];
  const float* b_hh0 = (const float*)d_in[5];
  const float* W_ih1 = (const float*)d_in[6];
  const float* W_hh1 = (const float*)d_in[7];
  const float* b_ih1 = (const float*)d_in[8];
  const float* b_hh1 = (const float*)d_in[9];
  const float* Wb    = (const float*)d_in[10];
  const float* bb    = (const float*)d_in[11];
  const float* ln_g  = (const float*)d_in[12];
  const float* ln_b  = (const float*)d_in[13];
  const float* W1a   = (const float*)d_in[14];
  const float* b1a   = (const float*)d_in[15];
  const float* W2a   = (const float*)d_in[16];
  const float* b2a   = (const float*)d_in[17];
  const float* va    = (const float*)d_in[18];
  const float* ba    = (const float*)d_in[19];
  const float* Wd_ih = (const float*)d_in[20];
  const float* Wd_hh = (const float*)d_in[21];
  const float* bd_ih = (const float*)d_in[22];
  const float* bd_hh = (const float*)d_in[23];
  const float* Wo1   = (const float*)d_in[24];
  const float* bo1   = (const float*)d_in[25];
  const float* Wo2   = (const float*)d_in[26];
  const float* bo2   = (const float*)d_in[27];
  float* out = (float*)d_out;
  (void)in_sizes; (void)n_in; (void)out_size;

  unsigned char* wsb = (unsigned char*)d_ws;
  size_t off = 0;
  auto alloc = [&](size_t bytes) -> void* {
    void* p = wsb + off;
    off += (bytes + 255) & ~(size_t)255;
    return p;
  };
  // ---- persistent (weights, biases) ----
  u16* wih0b = (u16*)alloc(1024 * 32 * 2);    // padded K 6->32
  u16* whh0b = (u16*)alloc(1024 * 256 * 2);
  u16* wih1b = (u16*)alloc(1024 * 256 * 2);
  u16* whh1b = (u16*)alloc(1024 * 256 * 2);
  u16* wdihb = (u16*)alloc(1024 * 416 * 2);   // padded K 390->416
  u16* wdhhb = (u16*)alloc(1024 * 256 * 2);
  u16* w1ab  = (u16*)alloc(256 * 256 * 2);
  u16* w2ab  = (u16*)alloc(256 * 256 * 2);
  u16* wo1b  = (u16*)alloc(128 * 256 * 2);
  float* bsum0 = (float*)alloc(1024 * 4);
  float* bsum1 = (float*)alloc(1024 * 4);
  float* bsumd = (float*)alloc(1024 * 4);

  // ---- batch chunking: per-row bytes ----
  const long perRow = 6656;
  long avail = (long)ws_size - (long)off - 32768;
  long R = avail > 0 ? avail / perRow : 128;
  R &= ~127L;
  if (R > BATCH) R = BATCH;
  if (R < 128) R = 128;

  u16* xbf    = (u16*)alloc((size_t)R * 96 * 2);    // [R*3][32] padded
  u16* y0     = (u16*)alloc((size_t)R * 768 * 2);   // layer0 outputs; later enc_proj
  u16* y1     = (u16*)alloc((size_t)R * 768 * 2);   // layer1 outputs = encoder_outputs
  float* cbuf = (float*)alloc((size_t)R * 256 * 4); // c: layer0, layer1, decoder
  u16* hdec0  = (u16*)alloc((size_t)R * 256 * 2);
  u16* hdec1  = (u16*)alloc((size_t)R * 256 * 2);
  u16* qt1    = (u16*)alloc((size_t)R * 256 * 2);   // q then t1
  u16* dec_in = (u16*)alloc((size_t)R * 416 * 2);   // [R][416], cols 390..415 zero

  // ---- fused prep (single launch) ----
  {
    PrepP p;
    const float* ss[9] = {W_ih0, W_hh0, W_ih1, W_hh1, Wd_ih, Wd_hh, W1a, W2a, Wo1};
    u16* dd[9]         = {wih0b, whh0b, wih1b, whh1b, wdihb, wdhhb, w1ab, w2ab, wo1b};
    int scv[9]         = {6, 256, 256, 256, 390, 256, 256, 256, 256};
    int dcv[9]         = {32, 256, 256, 256, 416, 256, 256, 256, 256};
    long rows[9]       = {1024, 1024, 1024, 1024, 1024, 1024, 256, 256, 128};
    long cvtTotal = 0;
    for (int i = 0; i < 9; ++i) {
      p.s[i] = ss[i]; p.d[i] = dd[i]; p.sc[i] = scv[i]; p.dc[i] = dcv[i];
      p.n[i] = rows[i] * dcv[i]; cvtTotal += p.n[i];
    }
    p.ba[0] = b_ih0; p.bb_[0] = b_hh0; p.bo[0] = bsum0;
    p.ba[1] = b_ih1; p.bb_[1] = b_hh1; p.bo[1] = bsum1;
    p.ba[2] = bd_ih; p.bb_[2] = bd_hh; p.bo[2] = bsumd;
    prep_kernel<<<dim3(2048), dim3(256), 0, stream>>>(p, cvtTotal, cvtTotal + 3072);
  }

  const dim3 blk(256);

  for (long r0 = 0; r0 < BATCH; r0 += R) {
    const long Rc = (BATCH - r0 < R) ? (BATCH - r0) : R;
    const unsigned nb = (unsigned)(Rc / 128);
    const dim3 gcell(nb, 4);
    const float* cbc_c  = cbc + r0 * 18;
    const float* base_c = base + r0 * 10;
    float* out_c = out + r0 * 30;

    front_kernel<<<dim3((unsigned)(Rc / 4)), blk, 0, stream>>>(
        cbc_c, base_c, Wb, bb, ln_g, ln_b, dec_in, xbf);

    // ---- encoder layer 0 (K1 padded to 32) ----
    for (int t = 0; t < 3; ++t) {
      const u16* a2 = t ? (y0 + (t - 1) * 256) : nullptr;
      mfma_gemm4<1, 4><<<gcell, blk, 0, stream>>>(
          xbf + t * 32, 96, 32, wih0b, 32,
          a2, 768, 256, whh0b, 256,
          256, 64, bsum0,
          nullptr, 0, 0,
          (t ? cbuf : nullptr), cbuf, y0 + t * 256, 768);
    }
    // ---- encoder layer 1 ----
    for (int t = 0; t < 3; ++t) {
      const u16* a2 = t ? (y1 + (t - 1) * 256) : nullptr;
      mfma_gemm4<1, 4><<<gcell, blk, 0, stream>>>(
          y0 + t * 256, 768, 256, wih1b, 256,
          a2, 768, 256, whh1b, 256,
          256, 64, bsum1,
          nullptr, 0, 0,
          (t ? cbuf : nullptr), cbuf, y1 + t * 256, 768);
    }
    // ---- enc_proj = encoder_outputs @ W2a^T + b2a (into y0, now dead) ----
    mfma_gemm4<0, 4><<<dim3(nb * 3, 1), blk, 0, stream>>>(
        y1, 256, 256, w2ab, 256,
        nullptr, 0, 0, nullptr, 0,
        64, 0, b2a,
        y0, 256, 0,
        nullptr, nullptr, nullptr, 0);

    // ---- decoder ----
    const u16* hcur = y1 + 2 * 256; long hld = 768;   // hT
    for (int s = 0; s < 5; ++s) {
      // q = h @ W1a^T + b1a  (2 column-halves for 2x blocks)
      mfma_gemm4<0, 2><<<dim3(nb, 2), blk, 0, stream>>>(
          hcur, hld, 256, w1ab, 256,
          nullptr, 0, 0, nullptr, 0,
          64, 128, b1a,
          qt1, 256, 0,
          nullptr, nullptr, nullptr, 0);
      // attention -> context into dec_in[:, 6:262]
      attn_kernel<<<dim3((unsigned)(Rc / 4)), blk, 0, stream>>>(qt1, y0, y1, va, ba, dec_in);
      // decoder LSTM cell (K1 padded to 416)
      u16* hnext = (s & 1) ? hdec1 : hdec0;
      mfma_gemm4<1, 4><<<gcell, blk, 0, stream>>>(
          dec_in, 416, 416, wdihb, 416,
          hcur, hld, 256, wdhhb, 256,
          256, 64, bsumd,
          nullptr, 0, 0,
          cbuf, cbuf, hnext, 256);
      hcur = hnext; hld = 256;
      // t1 = relu(h @ Wo1^T + bo1)
      mfma_gemm4<0, 2><<<dim3(nb, 1), blk, 0, stream>>>(
          hcur, 256, 256, wo1b, 256,
          nullptr, 0, 0, nullptr, 0,
          64, 0, bo1,
          qt1, 128, 1,
          nullptr, nullptr, nullptr, 0);
      // delta + pred
      const float* lastp = (s == 0) ? (cbc_c + 12) : (out_c + (long)(s - 1) * 6);
      const int lstr = (s == 0) ? 18 : 30;
      delta_kernel<<<dim3((unsigned)(Rc / 64)), blk, 0, stream>>>(
          qt1, Wo2, bo2, lastp, lstr, out_c + (long)s * 6, 30, dec_in);
    }
  }
}